// Round 8
// baseline (3994.666 us; speedup 1.0000x reference)
//
#include <hip/hip_runtime.h>
#include <hip/hip_bf16.h>
#include <math.h>

#define N_NODES 50000
#define E_EDGES 1600000
#define EP_EDGES (E_EDGES + N_NODES)
#define IN_F 512
#define HID 256
#define HEADS 8
#define OUTF 128

typedef unsigned short u16;
typedef __attribute__((ext_vector_type(8))) short short8;
typedef __attribute__((ext_vector_type(4))) float floatx4;

static __device__ __forceinline__ float eluf(float x) {
  return x > 0.f ? x : expm1f(x);
}

static __device__ __forceinline__ u16 bf16_hi(float v) {
  __hip_bfloat16 h = __float2bfloat16(v);
  return *(u16*)&h;
}
static __device__ __forceinline__ float bf16_f(u16 u) {
  __hip_bfloat16 h = *(__hip_bfloat16*)&u;
  return __bfloat162float(h);
}
// 3-way split: v ~= h + m + l, each bf16 (~24 mantissa bits total)
static __device__ __forceinline__ void split3_bf16(float v, u16& h, u16& m, u16& l) {
  h = bf16_hi(v);
  float r1 = v - bf16_f(h);
  m = bf16_hi(r1);
  float r2 = r1 - bf16_f(m);
  l = bf16_hi(r2);
}

// clamp index to [0, n)
static __device__ __forceinline__ int clampi(int v, int n) {
  return v < 0 ? 0 : (v >= n ? n - 1 : v);
}

// ---------------- CSR build ----------------

__global__ void k_detect(const int* __restrict__ ei, int* __restrict__ flag) {
  __shared__ int nz;
  if (threadIdx.x == 0) nz = 0;
  __syncthreads();
  for (int i = threadIdx.x; i < 4096; i += blockDim.x)
    if (ei[2 * i + 1] != 0) nz = 1;   // benign race
  __syncthreads();
  if (threadIdx.x == 0) *flag = (nz ? 0 : 1);
}

__global__ void k_init_deg(int* __restrict__ deg, int n) {
  int i = blockIdx.x * 256 + threadIdx.x;
  if (i < n) deg[i] = 1;   // self loop
}

__global__ void k_count(const int* __restrict__ ei, const int* __restrict__ flag,
                        int* __restrict__ deg, int E) {
  int e = blockIdx.x * 256 + threadIdx.x;
  if (e >= E) return;
  int f = *flag;
  int idx = E + e;                       // row 1 = dst
  int dst = clampi(ei[f ? 2 * idx : idx], N_NODES);
  atomicAdd(&deg[dst], 1);
}

// wave-shfl based scan: inclusive scan of deg -> rp[1..n], rp[0]=0.
__global__ __launch_bounds__(1024) void k_scan(const int* __restrict__ deg,
                                               int* __restrict__ rp, int n) {
  __shared__ int sw[16];
  __shared__ int s_run;
  int tid = threadIdx.x, lane = tid & 63, w = tid >> 6;
  if (tid == 0) s_run = 0;
  __syncthreads();
  for (int base = 0; base < n; base += 1024) {
    int i = base + tid;
    int v = (i < n) ? deg[i] : 0;
    int sv = v;
#pragma unroll
    for (int off = 1; off < 64; off <<= 1) {
      int t = __shfl_up(sv, off);
      if (lane >= off) sv += t;
    }
    if (lane == 63) sw[w] = sv;
    __syncthreads();
    if (w == 0) {
      int wsum = (lane < 16) ? sw[lane] : 0;
#pragma unroll
      for (int off = 1; off < 16; off <<= 1) {
        int t = __shfl_up(wsum, off);
        if (lane >= off) wsum += t;
      }
      if (lane < 16) sw[lane] = wsum;
    }
    __syncthreads();
    int woff = (w > 0) ? sw[w - 1] : 0;
    int run = s_run;
    if (i < n) rp[i + 1] = run + woff + sv;
    __syncthreads();
    if (tid == 1023) s_run = run + sw[15];
    __syncthreads();
  }
  if (tid == 0) rp[0] = 0;
}

__global__ void k_fill_self(const int* __restrict__ rp, int* __restrict__ wp,
                            int* __restrict__ col, int n) {
  int i = blockIdx.x * 256 + threadIdx.x;
  if (i < n) { int p = rp[i]; col[p] = i; wp[i] = p + 1; }
}

__global__ void k_fill_edges(const int* __restrict__ ei, const int* __restrict__ flag,
                             int* __restrict__ wp, int* __restrict__ col, int E) {
  int e = blockIdx.x * 256 + threadIdx.x;
  if (e >= E) return;
  int f = *flag;
  int src = clampi(ei[f ? 2 * e : e], N_NODES);
  int didx = E + e;
  int dst = clampi(ei[f ? 2 * didx : didx], N_NODES);
  int p = atomicAdd(&wp[dst], 1);
  col[p] = src;
}

// ---------------- weight transpose + 3-way split ----------------
__global__ void k_split3_t(const float* __restrict__ W, u16* __restrict__ H,
                           u16* __restrict__ Mv, u16* __restrict__ L,
                           int kshift, int kmask, int Nw, int total) {
  int idx = blockIdx.x * 256 + threadIdx.x;
  if (idx >= total) return;
  int n = idx >> kshift;
  int k = idx & kmask;
  u16 h, m, l;
  split3_bf16(W[(size_t)k * Nw + n], h, m, l);
  H[idx] = h;
  Mv[idx] = m;
  L[idx] = l;
}

// ---------------- attention projection: w_att = W1_h @ att ----------------
__global__ __launch_bounds__(256) void k_watt1(
    const float* __restrict__ W1, const float* __restrict__ attS,
    const float* __restrict__ attD, float* __restrict__ watt) {
  int wid = (blockIdx.x * 256 + threadIdx.x) >> 6;   // one wave per (k,h)
  int lane = threadIdx.x & 63;
  if (wid >= IN_F * HEADS) return;
  int k = wid >> 3, h = wid & 7;
  float4 wv = *(const float4*)&W1[(size_t)k * (HID * HEADS) + h * HID + lane * 4];
  float4 sv = *(const float4*)&attS[h * HID + lane * 4];
  float4 dv = *(const float4*)&attD[h * HID + lane * 4];
  float s = wv.x * sv.x + wv.y * sv.y + wv.z * sv.z + wv.w * sv.w;
  float d = wv.x * dv.x + wv.y * dv.y + wv.z * dv.z + wv.w * dv.w;
  for (int off = 32; off; off >>= 1) {
    s += __shfl_xor(s, off);
    d += __shfl_xor(d, off);
  }
  if (lane == 0) {
    watt[(size_t)(2 * h) * IN_F + k] = s;
    watt[(size_t)(2 * h + 1) * IN_F + k] = d;
  }
}

// a_src/a_dst for ALL heads in one pass over x.
__global__ __launch_bounds__(256) void k_asad1(
    const float* __restrict__ x, const float* __restrict__ watt,
    float* __restrict__ asall, float* __restrict__ adall, int n) {
  int node = (blockIdx.x * 256 + threadIdx.x) >> 6;
  int lane = threadIdx.x & 63;
  if (node >= n) return;
  float4 x0 = *(const float4*)&x[(size_t)node * IN_F + lane * 8];
  float4 x1 = *(const float4*)&x[(size_t)node * IN_F + lane * 8 + 4];
  for (int h = 0; h < HEADS; ++h) {
    const float* ws = watt + (size_t)(2 * h) * IN_F + lane * 8;
    const float* wd = watt + (size_t)(2 * h + 1) * IN_F + lane * 8;
    float4 s0 = *(const float4*)ws, s1 = *(const float4*)(ws + 4);
    float4 d0 = *(const float4*)wd, d1 = *(const float4*)(wd + 4);
    float s = x0.x * s0.x + x0.y * s0.y + x0.z * s0.z + x0.w * s0.w
            + x1.x * s1.x + x1.y * s1.y + x1.z * s1.z + x1.w * s1.w;
    float d = x0.x * d0.x + x0.y * d0.y + x0.z * d0.z + x0.w * d0.w
            + x1.x * d1.x + x1.y * d1.y + x1.z * d1.z + x1.w * d1.w;
    for (int off = 32; off; off >>= 1) {
      s += __shfl_xor(s, off);
      d += __shfl_xor(d, off);
    }
    if (lane == 0) {
      asall[(size_t)h * n + node] = s;
      adall[(size_t)h * n + node] = d;
    }
  }
}

// ---------------- split-bf16 MFMA GEMM machinery ----------------
#define GBM 128
#define GBN 128
#define GBK 32
#define GM1 391   // ceil(50000/128)

#define MFMA_BF16 __builtin_amdgcn_mfma_f32_16x16x32_bf16

__device__ __forceinline__ void gemm_epilogue(floatx4 acc[4][4], float* C,
                                              int ldc, int M, int accum,
                                              int row0, int col0, int wr,
                                              int wc, int lane) {
  int q = lane >> 4, n15 = lane & 15;
#pragma unroll
  for (int i = 0; i < 4; ++i) {
#pragma unroll
    for (int r = 0; r < 4; ++r) {
      int row = row0 + wr * 64 + i * 16 + q * 4 + r;
      if (row < M) {
#pragma unroll
        for (int j = 0; j < 4; ++j) {
          int cg = col0 + wc * 64 + j * 16 + n15;
          float v = acc[i][j][r];
          if (accum) v += C[(size_t)row * ldc + cg];
          C[(size_t)row * ldc + cg] = v;
        }
      }
    }
  }
}

// GEMM1 core: A = x (fp32, split 3-way on the fly), B pre-split 3-way.
__device__ __forceinline__ void gemm1_core(
    const float* __restrict__ X, int lda,
    const u16* __restrict__ Bh, const u16* __restrict__ Bm,
    const u16* __restrict__ Bl, int ldb,
    float* __restrict__ C, int ldc, int M, int K, int row0, int col0,
    u16* lds) {
  int tid = threadIdx.x;
  int lane = tid & 63, wave = tid >> 6;
  int wr = wave >> 1, wc = wave & 1;
  floatx4 acc[4][4] = {};
  int m0 = tid >> 2, m1 = (tid + 256) >> 2;
  int q0 = tid & 3;
  int lo0 = ((m0 >> 4) * 64 + q0 * 16 + (m0 & 15)) * 8;
  int lo1 = ((m1 >> 4) * 64 + q0 * 16 + (m1 & 15)) * 8;

  for (int k0 = 0; k0 < K; k0 += GBK) {
#pragma unroll
    for (int c = 0; c < 2; ++c) {
      int m = c ? m1 : m0;
      int lo = c ? lo1 : lo0;
      int gr = row0 + m;
      float f[8];
      if (gr < M) {
        float4 f0 = *(const float4*)(X + (size_t)gr * lda + k0 + q0 * 8);
        float4 f1 = *(const float4*)(X + (size_t)gr * lda + k0 + q0 * 8 + 4);
        f[0] = f0.x; f[1] = f0.y; f[2] = f0.z; f[3] = f0.w;
        f[4] = f1.x; f[5] = f1.y; f[6] = f1.z; f[7] = f1.w;
      } else {
#pragma unroll
        for (int e = 0; e < 8; ++e) f[e] = 0.f;
      }
      short8 vh, vm, vl;
#pragma unroll
      for (int e = 0; e < 8; ++e) {
        u16 h, m2, l;
        split3_bf16(f[e], h, m2, l);
        vh[e] = (short)h; vm[e] = (short)m2; vl[e] = (short)l;
      }
      *(short8*)&lds[lo] = vh;
      *(short8*)&lds[4096 + lo] = vm;
      *(short8*)&lds[8192 + lo] = vl;
    }
#pragma unroll
    for (int c = 0; c < 2; ++c) {
      int m = c ? m1 : m0;
      int lo = c ? lo1 : lo0;
      size_t go = (size_t)(col0 + m) * ldb + k0 + q0 * 8;
      *(short8*)&lds[12288 + lo] = *(const short8*)(Bh + go);
      *(short8*)&lds[16384 + lo] = *(const short8*)(Bm + go);
      *(short8*)&lds[20480 + lo] = *(const short8*)(Bl + go);
    }
    __syncthreads();
    short8 a_h[4], a_m[4], a_l[4];
#pragma unroll
    for (int i = 0; i < 4; ++i) {
      int o = ((wr * 4 + i) * 64 + lane) * 8;
      a_h[i] = *(short8*)&lds[o];
      a_m[i] = *(short8*)&lds[4096 + o];
      a_l[i] = *(short8*)&lds[8192 + o];
    }
#pragma unroll
    for (int j = 0; j < 4; ++j) {
      int o = ((wc * 4 + j) * 64 + lane) * 8;
      short8 b_h = *(short8*)&lds[12288 + o];
      short8 b_m = *(short8*)&lds[16384 + o];
      short8 b_l = *(short8*)&lds[20480 + o];
#pragma unroll
      for (int i = 0; i < 4; ++i) {
        acc[i][j] = MFMA_BF16(a_l[i], b_h, acc[i][j], 0, 0, 0);
        acc[i][j] = MFMA_BF16(a_m[i], b_m, acc[i][j], 0, 0, 0);
        acc[i][j] = MFMA_BF16(a_h[i], b_l, acc[i][j], 0, 0, 0);
        acc[i][j] = MFMA_BF16(a_m[i], b_h, acc[i][j], 0, 0, 0);
        acc[i][j] = MFMA_BF16(a_h[i], b_m, acc[i][j], 0, 0, 0);
        acc[i][j] = MFMA_BF16(a_h[i], b_h, acc[i][j], 0, 0, 0);
      }
    }
    __syncthreads();
  }
  gemm_epilogue(acc, C, ldc, M, 0, row0, col0, wr, wc, lane);
}

__global__ __launch_bounds__(256) void gemm1_k(
    const float* __restrict__ X, int lda,
    const u16* __restrict__ Bh, const u16* __restrict__ Bm,
    const u16* __restrict__ Bl, int ldb,
    float* __restrict__ C, int ldc, int M, int K) {
  __shared__ __align__(16) u16 lds[24576];
  gemm1_core(X, lda, Bh, Bm, Bl, ldb, C, ldc, M, K,
             blockIdx.x * GBM, blockIdx.y * GBN, lds);
}

// 6-term core with pre-split A (used for h2). accum flag.
__device__ __forceinline__ void gemm_core6(
    const u16* __restrict__ Ah, const u16* __restrict__ Am,
    const u16* __restrict__ Al, int lda,
    const u16* __restrict__ Bh, const u16* __restrict__ Bm,
    const u16* __restrict__ Bl, int ldb,
    float* __restrict__ C, int ldc, int M, int K, int row0, int col0,
    int accum, u16* lds) {
  int tid = threadIdx.x;
  int lane = tid & 63, wave = tid >> 6;
  int wr = wave >> 1, wc = wave & 1;
  floatx4 acc[4][4] = {};
  int m0 = tid >> 2, m1 = (tid + 256) >> 2;
  int q0 = tid & 3;
  int lo0 = ((m0 >> 4) * 64 + q0 * 16 + (m0 & 15)) * 8;
  int lo1 = ((m1 >> 4) * 64 + q0 * 16 + (m1 & 15)) * 8;
  for (int k0 = 0; k0 < K; k0 += GBK) {
#pragma unroll
    for (int c = 0; c < 2; ++c) {
      int m = c ? m1 : m0;
      int lo = c ? lo1 : lo0;
      int gr = row0 + m;
      short8 vh = {}, vm = {}, vl = {};
      if (gr < M) {
        size_t go = (size_t)gr * lda + k0 + q0 * 8;
        vh = *(const short8*)(Ah + go);
        vm = *(const short8*)(Am + go);
        vl = *(const short8*)(Al + go);
      }
      *(short8*)&lds[lo] = vh;
      *(short8*)&lds[4096 + lo] = vm;
      *(short8*)&lds[8192 + lo] = vl;
      size_t go = (size_t)(col0 + m) * ldb + k0 + q0 * 8;
      *(short8*)&lds[12288 + lo] = *(const short8*)(Bh + go);
      *(short8*)&lds[16384 + lo] = *(const short8*)(Bm + go);
      *(short8*)&lds[20480 + lo] = *(const short8*)(Bl + go);
    }
    __syncthreads();
    short8 a_h[4], a_m[4], a_l[4];
#pragma unroll
    for (int i = 0; i < 4; ++i) {
      int o = ((wr * 4 + i) * 64 + lane) * 8;
      a_h[i] = *(short8*)&lds[o];
      a_m[i] = *(short8*)&lds[4096 + o];
      a_l[i] = *(short8*)&lds[8192 + o];
    }
#pragma unroll
    for (int j = 0; j < 4; ++j) {
      int o = ((wc * 4 + j) * 64 + lane) * 8;
      short8 b_h = *(short8*)&lds[12288 + o];
      short8 b_m = *(short8*)&lds[16384 + o];
      short8 b_l = *(short8*)&lds[20480 + o];
#pragma unroll
      for (int i = 0; i < 4; ++i) {
        acc[i][j] = MFMA_BF16(a_l[i], b_h, acc[i][j], 0, 0, 0);
        acc[i][j] = MFMA_BF16(a_m[i], b_m, acc[i][j], 0, 0, 0);
        acc[i][j] = MFMA_BF16(a_h[i], b_l, acc[i][j], 0, 0, 0);
        acc[i][j] = MFMA_BF16(a_m[i], b_h, acc[i][j], 0, 0, 0);
        acc[i][j] = MFMA_BF16(a_h[i], b_m, acc[i][j], 0, 0, 0);
        acc[i][j] = MFMA_BF16(a_h[i], b_h, acc[i][j], 0, 0, 0);
      }
    }
    __syncthreads();
  }
  gemm_epilogue(acc, C, ldc, M, accum, row0, col0, wr, wc, lane);
}

// 3-term (2-way split) core — used for h3. accum flag.
__device__ __forceinline__ void gemm_core3(
    const u16* __restrict__ Ah, const u16* __restrict__ Am, int lda,
    const u16* __restrict__ Bh, const u16* __restrict__ Bm, int ldb,
    float* __restrict__ C, int ldc, int M, int K, int row0, int col0,
    int accum, u16* lds) {
  int tid = threadIdx.x;
  int lane = tid & 63, wave = tid >> 6;
  int wr = wave >> 1, wc = wave & 1;
  floatx4 acc[4][4] = {};
  int m0 = tid >> 2, m1 = (tid + 256) >> 2;
  int q0 = tid & 3;
  int lo0 = ((m0 >> 4) * 64 + q0 * 16 + (m0 & 15)) * 8;
  int lo1 = ((m1 >> 4) * 64 + q0 * 16 + (m1 & 15)) * 8;
  for (int k0 = 0; k0 < K; k0 += GBK) {
#pragma unroll
    for (int c = 0; c < 2; ++c) {
      int m = c ? m1 : m0;
      int lo = c ? lo1 : lo0;
      int gr = row0 + m;
      short8 vh = {}, vm = {};
      if (gr < M) {
        size_t go = (size_t)gr * lda + k0 + q0 * 8;
        vh = *(const short8*)(Ah + go);
        vm = *(const short8*)(Am + go);
      }
      *(short8*)&lds[lo] = vh;
      *(short8*)&lds[4096 + lo] = vm;
      size_t go = (size_t)(col0 + m) * ldb + k0 + q0 * 8;
      *(short8*)&lds[12288 + lo] = *(const short8*)(Bh + go);
      *(short8*)&lds[16384 + lo] = *(const short8*)(Bm + go);
    }
    __syncthreads();
    short8 a_h[4], a_m[4];
#pragma unroll
    for (int i = 0; i < 4; ++i) {
      int o = ((wr * 4 + i) * 64 + lane) * 8;
      a_h[i] = *(short8*)&lds[o];
      a_m[i] = *(short8*)&lds[4096 + o];
    }
#pragma unroll
    for (int j = 0; j < 4; ++j) {
      int o = ((wc * 4 + j) * 64 + lane) * 8;
      short8 b_h = *(short8*)&lds[12288 + o];
      short8 b_m = *(short8*)&lds[16384 + o];
#pragma unroll
      for (int i = 0; i < 4; ++i) {
        acc[i][j] = MFMA_BF16(a_m[i], b_h, acc[i][j], 0, 0, 0);
        acc[i][j] = MFMA_BF16(a_h[i], b_m, acc[i][j], 0, 0, 0);
        acc[i][j] = MFMA_BF16(a_h[i], b_h, acc[i][j], 0, 0, 0);
      }
    }
    __syncthreads();
  }
  gemm_epilogue(acc, C, ldc, M, accum, row0, col0, wr, wc, lane);
}

// standalone GEMM2/3 (used for the final head and the fallback path)
__global__ __launch_bounds__(256) void gemm23_k(
    const u16* __restrict__ Ah, const u16* __restrict__ Am,
    const u16* __restrict__ Al, int lda,
    const u16* __restrict__ B2h, const u16* __restrict__ B2m,
    const u16* __restrict__ B2l,
    const u16* __restrict__ B3h, const u16* __restrict__ B3m, int ldb,
    float* __restrict__ C2, float* __restrict__ C3, int ldc, int M, int K,
    int accum) {
  __shared__ __align__(16) u16 lds[24576];
  if (blockIdx.z == 0)
    gemm_core6(Ah, Am, Al, lda, B2h, B2m, B2l, ldb, C2, ldc, M, K,
               blockIdx.x * GBM, 0, accum, lds);
  else
    gemm_core3(Ah, Am, lda, B3h, B3m, ldb, C3, ldc, M, K,
               blockIdx.x * GBM, 0, accum, lds);
}

// ---------------- attention dot products (layer 2, C=128 only) -----------
template <int C>
__global__ __launch_bounds__(256) void att_dot(
    const float* __restrict__ h, const float* __restrict__ attS,
    const float* __restrict__ attD, float* __restrict__ aS,
    float* __restrict__ aD, int n) {
  int node = (blockIdx.x * 256 + threadIdx.x) >> 6;
  int lane = threadIdx.x & 63;
  if (node >= n) return;
  float s = 0.f, d = 0.f;
  if (C == 256) {
    float4 hv = *(const float4*)&h[(size_t)node * C + lane * 4];
    float4 sv = *(const float4*)&attS[lane * 4];
    float4 dv = *(const float4*)&attD[lane * 4];
    s = hv.x * sv.x + hv.y * sv.y + hv.z * sv.z + hv.w * sv.w;
    d = hv.x * dv.x + hv.y * dv.y + hv.z * dv.z + hv.w * dv.w;
  } else {
    float2 hv = *(const float2*)&h[(size_t)node * C + lane * 2];
    float2 sv = *(const float2*)&attS[lane * 2];
    float2 dv = *(const float2*)&attD[lane * 2];
    s = hv.x * sv.x + hv.y * sv.y;
    d = hv.x * dv.x + hv.y * dv.y;
  }
  for (int off = 32; off; off >>= 1) {
    s += __shfl_xor(s, off);
    d += __shfl_xor(d, off);
  }
  if (lane == 0) { aS[node] = s; aD[node] = d; }
}

// ---------------- layer-1 fused softmax + gather-aggregate core -----------
static __device__ __forceinline__ void aggr_l1_core(
    int node, int lane,
    const int* __restrict__ rp, const int* __restrict__ col,
    const float* __restrict__ aS, const float* __restrict__ aD,
    const float* __restrict__ h, const float* __restrict__ bias,
    u16* __restrict__ embH, u16* __restrict__ embM, u16* __restrict__ embL,
    int ecol0, int ldE, int n) {
  int s0 = rp[node], s1 = rp[node + 1];
  int d = s1 - s0;
  float ad = aD[node];
  float4 acc = make_float4(0.f, 0.f, 0.f, 0.f);

  if (d <= 64) {
    int c = 0;
    float e = -3.0e38f;
    if (lane < d) {
      c = clampi(col[s0 + lane], n);
      float t = aS[c] + ad;
      e = t >= 0.f ? t : 0.2f * t;
    }
    float m = e;
    for (int off = 32; off; off >>= 1) m = fmaxf(m, __shfl_xor(m, off));
    float ex = (lane < d) ? expf(e - m) : 0.f;
    float s = ex;
    for (int off = 32; off; off >>= 1) s += __shfl_xor(s, off);
    float al = ex * (1.f / (s + 1e-16f));   // 0 for lanes >= d
    int d8 = d & ~7;
    for (int j = 0; j < d8; j += 8) {
#pragma unroll
      for (int t = 0; t < 8; ++t) {
        int ct = __shfl(c, j + t);
        float at = __shfl(al, j + t);
        float4 hv = *(const float4*)&h[(size_t)ct * HID + lane * 4];
        acc.x += at * hv.x; acc.y += at * hv.y;
        acc.z += at * hv.z; acc.w += at * hv.w;
      }
    }
    if (d8 < d) {
#pragma unroll
      for (int t = 0; t < 8; ++t) {
        if (d8 + t < d) {    // wave-uniform branch (d is per-wave scalar)
          int ct = __shfl(c, d8 + t);
          float at = __shfl(al, d8 + t);
          float4 hv = *(const float4*)&h[(size_t)ct * HID + lane * 4];
          acc.x += at * hv.x; acc.y += at * hv.y;
          acc.z += at * hv.z; acc.w += at * hv.w;
        }
      }
    }
  } else {
    float m = -3.0e38f;
    for (int i = s0 + lane; i < s1; i += 64) {
      float e = aS[clampi(col[i], n)] + ad;
      e = e >= 0.f ? e : 0.2f * e;
      m = fmaxf(m, e);
    }
    for (int off = 32; off; off >>= 1) m = fmaxf(m, __shfl_xor(m, off));
    float sum = 0.f;
    for (int i = s0 + lane; i < s1; i += 64) {
      float e = aS[clampi(col[i], n)] + ad;
      e = e >= 0.f ? e : 0.2f * e;
      sum += expf(e - m);
    }
    for (int off = 32; off; off >>= 1) sum += __shfl_xor(sum, off);
    float inv = 1.f / (sum + 1e-16f);
    for (int i = s0; i < s1; ++i) {
      int ci = clampi(col[i], n);
      float e = aS[ci] + ad;
      e = e >= 0.f ? e : 0.2f * e;
      float a = expf(e - m) * inv;
      float4 hv = *(const float4*)&h[(size_t)ci * HID + lane * 4];
      acc.x += a * hv.x; acc.y += a * hv.y; acc.z += a * hv.z; acc.w += a * hv.w;
    }
  }

  float4 bb = *(const float4*)&bias[lane * 4];
  float v0 = eluf(acc.x + bb.x);
  float v1 = eluf(acc.y + bb.y);
  float v2 = eluf(acc.z + bb.z);
  float v3 = eluf(acc.w + bb.w);
  ushort4 uh, um, ul;
  split3_bf16(v0, uh.x, um.x, ul.x);
  split3_bf16(v1, uh.y, um.y, ul.y);
  split3_bf16(v2, uh.z, um.z, ul.z);
  split3_bf16(v3, uh.w, um.w, ul.w);
  size_t o = (size_t)node * ldE + ecol0 + lane * 4;
  *(ushort4*)&embH[o] = uh;
  *(ushort4*)&embM[o] = um;
  *(ushort4*)&embL[o] = ul;
}

__global__ __launch_bounds__(256) void aggr_l1_fused(
    const int* __restrict__ rp, const int* __restrict__ col,
    const float* __restrict__ aS, const float* __restrict__ aD,
    const float* __restrict__ h, const float* __restrict__ bias,
    u16* __restrict__ embH, u16* __restrict__ embM, u16* __restrict__ embL,
    int ecol0, int ldE, int n) {
  int node = (blockIdx.x * 256 + threadIdx.x) >> 6;
  int lane = threadIdx.x & 63;
  if (node >= n) return;
  aggr_l1_core(node, lane, rp, col, aS, aD, h, bias, embH, embM, embL,
               ecol0, ldE, n);
}

// ---------------- fused pipeline step ----------------
// One dispatch runs three independent roles (block-level):
//   role A (bulk): aggr(h)       — fabric-bound random gather
//   role B:        gemm1(h+1)    — MFMA-bound          (nG1 blocks)
//   role C:        gemm23(h-1)   — MFMA-bound          (nG23 blocks)
// Compute blocks are striped at every 9th blockIdx so each CU holds an
// ~8:1 aggr:gemm mix throughout the dispatch (overlap, not phases).
__global__ __launch_bounds__(256) void fused_step(
    // role A
    const int* __restrict__ rp, const int* __restrict__ col,
    const float* __restrict__ aS, const float* __restrict__ aD,
    const float* __restrict__ hg, const float* __restrict__ bias,
    u16* __restrict__ embH, u16* __restrict__ embM, u16* __restrict__ embL,
    int ecol0, int ldE, int n,
    // role B
    const float* __restrict__ X,
    const u16* __restrict__ B1h, const u16* __restrict__ B1m,
    const u16* __restrict__ B1l, float* __restrict__ h1out, int nG1,
    // role C
    const u16* __restrict__ A23h, const u16* __restrict__ A23m,
    const u16* __restrict__ A23l,
    const u16* __restrict__ B2h, const u16* __restrict__ B2m,
    const u16* __restrict__ B2l,
    const u16* __restrict__ B3h, const u16* __restrict__ B3m,
    float* __restrict__ C2, float* __restrict__ C3, int accum, int nG23) {
  __shared__ __align__(16) u16 lds[24576];
  int nC = nG1 + nG23;
  int k = blockIdx.x;
  int q = k / 9, r = k - q * 9;
  if (r == 0 && q < nC) {
    if (q < nG1) {
      int bx = q % GM1, by = q / GM1;
      gemm1_core(X, IN_F, B1h, B1m, B1l, IN_F, h1out, HID, n, IN_F,
                 bx * GBM, by * GBN, lds);
    } else {
      int p = q - nG1;
      int z = p / GM1, bx = p - z * GM1;
      if (z == 0)
        gemm_core6(A23h, A23m, A23l, ldE, B2h, B2m, B2l, HID * HEADS,
                   C2, OUTF, n, HID, bx * GBM, 0, accum, lds);
      else
        gemm_core3(A23h, A23m, ldE, B3h, B3m, HID * HEADS,
                   C3, OUTF, n, HID, bx * GBM, 0, accum, lds);
    }
    return;
  }
  int skipped = q + (r ? 1 : 0);
  if (skipped > nC) skipped = nC;
  int aggrIdx = k - skipped;
  int node = aggrIdx * 4 + (threadIdx.x >> 6);
  int lane = threadIdx.x & 63;
  if (node >= n) return;
  aggr_l1_core(node, lane, rp, col, aS, aD, hg, bias, embH, embM, embL,
               ecol0, ldE, n);
}

// ---------------- layer-2 fused softmax + gather + row-softmax ------------
__global__ __launch_bounds__(256) void aggr_l2_fused(
    const int* __restrict__ rp, const int* __restrict__ col,
    const float* __restrict__ aS, const float* __restrict__ aD,
    const float* __restrict__ h, const float* __restrict__ bias,
    float* __restrict__ out, float* __restrict__ pred, int n) {
  int node = (blockIdx.x * 256 + threadIdx.x) >> 6;
  int lane = threadIdx.x & 63;
  if (node >= n) return;
  int s0 = rp[node], s1 = rp[node + 1];
  int d = s1 - s0;
  float ad = aD[node];
  float2 acc = make_float2(0.f, 0.f);

  if (d <= 64) {
    int c = 0;
    float e = -3.0e38f;
    if (lane < d) {
      c = clampi(col[s0 + lane], n);
      float t = aS[c] + ad;
      e = t >= 0.f ? t : 0.2f * t;
    }
    float m = e;
    for (int off = 32; off; off >>= 1) m = fmaxf(m, __shfl_xor(m, off));
    float ex = (lane < d) ? expf(e - m) : 0.f;
    float s = ex;
    for (int off = 32; off; off >>= 1) s += __shfl_xor(s, off);
    float al = ex * (1.f / (s + 1e-16f));
    int d8 = d & ~7;
    for (int j = 0; j < d8; j += 8) {
#pragma unroll
      for (int t = 0; t < 8; ++t) {
        int ct = __shfl(c, j + t);
        float at = __shfl(al, j + t);
        float2 hv = *(const float2*)&h[(size_t)ct * OUTF + lane * 2];
        acc.x += at * hv.x; acc.y += at * hv.y;
      }
    }
    if (d8 < d) {
#pragma unroll
      for (int t = 0; t < 8; ++t) {
        if (d8 + t < d) {   // wave-uniform
          int ct = __shfl(c, d8 + t);
          float at = __shfl(al, d8 + t);
          float2 hv = *(const float2*)&h[(size_t)ct * OUTF + lane * 2];
          acc.x += at * hv.x; acc.y += at * hv.y;
        }
      }
    }
  } else {
    float m = -3.0e38f;
    for (int i = s0 + lane; i < s1; i += 64) {
      float e = aS[clampi(col[i], n)] + ad;
      e = e >= 0.f ? e : 0.2f * e;
      m = fmaxf(m, e);
    }
    for (int off = 32; off; off >>= 1) m = fmaxf(m, __shfl_xor(m, off));
    float sum = 0.f;
    for (int i = s0 + lane; i < s1; i += 64) {
      float e = aS[clampi(col[i], n)] + ad;
      e = e >= 0.f ? e : 0.2f * e;
      sum += expf(e - m);
    }
    for (int off = 32; off; off >>= 1) sum += __shfl_xor(sum, off);
    float inv = 1.f / (sum + 1e-16f);
    for (int i = s0; i < s1; ++i) {
      int ci = clampi(col[i], n);
      float e = aS[ci] + ad;
      e = e >= 0.f ? e : 0.2f * e;
      float a = expf(e - m) * inv;
      float2 hv = *(const float2*)&h[(size_t)ci * OUTF + lane * 2];
      acc.x += a * hv.x; acc.y += a * hv.y;
    }
  }

  float2 bb = *(const float2*)&bias[lane * 2];
  acc.x += bb.x; acc.y += bb.y;

  // ---- fused row softmax + argmax ----
  float bv;
  int bi;
  if (acc.y > acc.x) { bv = acc.y; bi = 2 * lane + 1; }
  else               { bv = acc.x; bi = 2 * lane; }
  for (int off = 32; off; off >>= 1) {
    float ov = __shfl_xor(bv, off);
    int oi = __shfl_xor(bi, off);
    if (ov > bv || (ov == bv && oi < bi)) { bv = ov; bi = oi; }
  }
  float e0 = expf(acc.x - bv), e1 = expf(acc.y - bv);
  float ssum = e0 + e1;
  for (int off = 32; off; off >>= 1) ssum += __shfl_xor(ssum, off);
  float2 r;
  r.x = e0 / ssum;
  r.y = e1 / ssum;
  *(float2*)&out[(size_t)node * OUTF + lane * 2] = r;
  if (pred != nullptr && lane == 0) pred[node] = (float)bi;
}

// ---------------- host orchestration ----------------
extern "C" void kernel_launch(void* const* d_in, const int* in_sizes, int n_in,
                              void* d_out, int out_size, void* d_ws, size_t ws_size,
                              hipStream_t stream) {
  const int N = N_NODES, E = E_EDGES;
  const float* x     = (const float*)d_in[0];
  const int*   ei1   = (const int*)d_in[1];
  const int*   ei2   = (const int*)d_in[2];
  const float* W1    = (const float*)d_in[3];
  const float* attS1 = (const float*)d_in[4];
  const float* attD1 = (const float*)d_in[5];
  const float* b1    = (const float*)d_in[6];
  const float* W2    = (const float*)d_in[7];
  const float* attS2 = (const float*)d_in[8];
  const float* attD2 = (const float*)d_in[9];
  const float* b2    = (const float*)d_in[10];
  const float* W3    = (const float*)d_in[11];
  const float* attS3 = (const float*)d_in[12];
  const float* attD3 = (const float*)d_in[13];
  const float* b3    = (const float*)d_in[14];

  // ---- decide pipelined vs fallback by workspace size ----
  // pipelined: h1h x2 (102.4MB) + 2-head emb (153.6MB) + everything else
  size_t needPipe =
      2 * ((size_t)EP_EDGES * 4) + 2 * ((size_t)(N + 1) * 4) +
      2 * ((size_t)N * 4) + 4096 +
      2 * ((size_t)N * HID * 4) +                      // h1h x2
      3 * ((size_t)N * 512 * 2) +                      // emb (2-head wide)
      (size_t)N * OUTF * 4 * 2 +                       // h2+h3
      3 * ((size_t)IN_F * HID * HEADS * 2) +           // W1T
      6 * ((size_t)HID * HEADS * OUTF * 2) +           // W2T/W3T
      2 * ((size_t)HEADS * N * 4) +                    // asall/adall
      4 * ((size_t)N * 4) +                            // as2..ad3
      (size_t)2 * HEADS * IN_F * 4 +                   // watt
      (size_t)(8 << 20);                               // slack
  int pipe = (ws_size >= needPipe) ? 1 : 0;
  const int nbuf = pipe ? 2 : 1;
  const int ldE = pipe ? 512 : 256;

  char* ws = (char*)d_ws;
  size_t off = 0;
  auto take = [&](size_t bytes) {
    off = (off + 255) & ~(size_t)255;
    size_t o = off;
    off += bytes;
    return o;
  };
  int*   col1 = (int*)(ws + take((size_t)EP_EDGES * 4));
  int*   col2 = (int*)(ws + take((size_t)EP_EDGES * 4));
  int*   rp1  = (int*)(ws + take((size_t)(N + 1) * 4));
  int*   rp2  = (int*)(ws + take((size_t)(N + 1) * 4));
  int*   wp1  = (int*)(ws + take((size_t)N * 4));
  int*   wp2  = (int*)(ws + take((size_t)N * 4));
  int*   flag = (int*)(ws + take(256));
  float* h1hA = (float*)(ws + take((size_t)N * HID * 4 * nbuf));
  float* h1hB = pipe ? h1hA + (size_t)N * HID : h1hA;
  u16*   embH = (u16*)(ws + take((size_t)N * ldE * 2));
  u16*   embM = (u16*)(ws + take((size_t)N * ldE * 2));
  u16*   embL = (u16*)(ws + take((size_t)N * ldE * 2));
  float* h2   = (float*)(ws + take((size_t)N * OUTF * 4 * 2));  // h2+h3
  float* h3   = h2 + (size_t)N * OUTF;
  u16*   W1Th = (u16*)(ws + take((size_t)IN_F * HID * HEADS * 2));  // [2048][512]
  u16*   W1Tm = (u16*)(ws + take((size_t)IN_F * HID * HEADS * 2));
  u16*   W1Tl = (u16*)(ws + take((size_t)IN_F * HID * HEADS * 2));
  u16*   W2Th = (u16*)(ws + take((size_t)HID * HEADS * OUTF * 2)); // [128][2048]
  u16*   W2Tm = (u16*)(ws + take((size_t)HID * HEADS * OUTF * 2));
  u16*   W2Tl = (u16*)(ws + take((size_t)HID * HEADS * OUTF * 2));
  u16*   W3Th = (u16*)(ws + take((size_t)HID * HEADS * OUTF * 2));
  u16*   W3Tm = (u16*)(ws + take((size_t)HID * HEADS * OUTF * 2));
  u16*   W3Tl = (u16*)(ws + take((size_t)HID * HEADS * OUTF * 2)); // dummy L
  float* asall = (float*)(ws + take((size_t)HEADS * N * 4));
  float* adall = (float*)(ws + take((size_t)HEADS * N * 4));
  float* as2  = (float*)(ws + take((size_t)N * 4));
  float* ad2  = (float*)(ws + take((size_t)N * 4));
  float* as3  = (float*)(ws + take((size_t)N * 4));
  float* ad3  = (float*)(ws + take((size_t)N * 4));
  float* watt = (float*)(ws + take((size_t)2 * HEADS * IN_F * 4));

  float* outp = (float*)d_out;
  float* x1   = outp;                         // logits   [N,128]
  float* x2   = outp + (size_t)N * OUTF;      // logits_2 [N,128]
  float* pred = outp + (size_t)2 * N * OUTF;  // predictions [N]

  const int gN = (N + 255) / 256;
  const int gE = (E + 255) / 256;
  const int gW = (N + 3) / 4;                 // one wave per node = 12500

  // ---- weight transpose + 3-way splits ----
  k_split3_t<<<(IN_F * HID * HEADS + 255) / 256, 256, 0, stream>>>(
      W1, W1Th, W1Tm, W1Tl, 9, 511, HID * HEADS, IN_F * HID * HEADS);
  k_split3_t<<<(HID * HEADS * OUTF + 255) / 256, 256, 0, stream>>>(
      W2, W2Th, W2Tm, W2Tl, 11, 2047, OUTF, HID * HEADS * OUTF);
  k_split3_t<<<(HID * HEADS * OUTF + 255) / 256, 256, 0, stream>>>(
      W3, W3Th, W3Tm, W3Tl, 11, 2047, OUTF, HID * HEADS * OUTF);

  // ---- layer-1 attention coefficients for ALL heads from x directly ----
  k_watt1<<<(IN_F * HEADS * 64 + 255) / 256, 256, 0, stream>>>(
      W1, attS1, attD1, watt);
  k_asad1<<<gW, 256, 0, stream>>>(x, watt, asall, adall, N);

  // ---- edge dtype detection + CSR build (both graphs) ----
  k_detect<<<1, 256, 0, stream>>>(ei1, flag);

  k_init_deg<<<gN, 256, 0, stream>>>(wp1, N);
  k_count<<<gE, 256, 0, stream>>>(ei1, flag, wp1, E);
  k_scan<<<1, 1024, 0, stream>>>(wp1, rp1, N);
  k_fill_self<<<gN, 256, 0, stream>>>(rp1, wp1, col1, N);
  k_fill_edges<<<gE, 256, 0, stream>>>(ei1, flag, wp1, col1, E);

  k_init_deg<<<gN, 256, 0, stream>>>(wp2, N);
  k_count<<<gE, 256, 0, stream>>>(ei2, flag, wp2, E);
  k_scan<<<1, 1024, 0, stream>>>(wp2, rp2, N);
  k_fill_self<<<gN, 256, 0, stream>>>(rp2, wp2, col2, N);
  k_fill_edges<<<gE, 256, 0, stream>>>(ei2, flag, wp2, col2, E);

  if (pipe) {
    // ---- software-pipelined layer 1: aggr(h) || gemm1(h+1) || gemm23(h-1) --
    float* buf[2] = {h1hA, h1hB};
    gemm1_k<<<dim3(GM1, 2), 256, 0, stream>>>(
        x, IN_F, W1Th, W1Tm, W1Tl, IN_F, buf[0], HID, N, IN_F);
    for (int h = 0; h < HEADS; ++h) {
      int nG1 = (h + 1 < HEADS) ? GM1 * 2 : 0;
      int nG23 = (h >= 1) ? GM1 * 2 : 0;
      int nC = nG1 + nG23;
      int T = gW + nC;
      if (9 * nC > T) T = 9 * nC;
      int hn = (h + 1 < HEADS) ? h + 1 : h;       // safe pointer when unused
      int hp = (h >= 1) ? h - 1 : 0;
      int sp = hp & 1;
      fused_step<<<T, 256, 0, stream>>>(
          rp1, col1, asall + (size_t)h * N, adall + (size_t)h * N,
          buf[h & 1], b1 + (size_t)h * HID,
          embH, embM, embL, (h & 1) * HID, ldE, N,
          x, W1Th + (size_t)hn * HID * IN_F, W1Tm + (size_t)hn * HID * IN_F,
          W1Tl + (size_t)hn * HID * IN_F, buf[(h + 1) & 1], nG1,
          embH + sp * HID, embM + sp * HID, embL + sp * HID,
          W2Th + (size_t)hp * HID, W2Tm + (size_t)hp * HID,
          W2Tl + (size_t)hp * HID,
          W3Th + (size_t)hp * HID, W3Tm + (size_t)hp * HID,
          h2, h3, hp > 0 ? 1 : 0, nG23);
    }
    // final gemm23 for head 7 (emb slot 1)
    gemm23_k<<<dim3(GM1, 1, 2), 256, 0, stream>>>(
        embH + HID, embM + HID, embL + HID, ldE,
        W2Th + (size_t)7 * HID, W2Tm + (size_t)7 * HID, W2Tl + (size_t)7 * HID,
        W3Th + (size_t)7 * HID, W3Tm + (size_t)7 * HID, HID * HEADS,
        h2, h3, OUTF, N, HID, 1);
  } else {
    // ---- fallback: sequential per-head ----
    for (int h = 0; h < HEADS; ++h) {
      gemm1_k<<<dim3(GM1, 2), 256, 0, stream>>>(
          x, IN_F,
          W1Th + (size_t)h * HID * IN_F, W1Tm + (size_t)h * HID * IN_F,
          W1Tl + (size_t)h * HID * IN_F, IN_F, h1hA, HID, N, IN_F);
      aggr_l1_fused<<<gW, 256, 0, stream>>>(
          rp1, col1, asall + (size_t)h * N, adall + (size_t)h * N, h1hA,
          b1 + (size_t)h * HID, embH, embM, embL, 0, ldE, N);
      gemm23_k<<<dim3(GM1, 1, 2), 256, 0, stream>>>(
          embH, embM, embL, ldE,
          W2Th + (size_t)h * HID, W2Tm + (size_t)h * HID,
          W2Tl + (size_t)h * HID,
          W3Th + (size_t)h * HID, W3Tm + (size_t)h * HID, HID * HEADS,
          h2, h3, OUTF, N, HID, h > 0 ? 1 : 0);
    }
  }

  // ---- layer 2 attention + aggregation (heads=1), softmax fused ----
  att_dot<OUTF><<<gW, 256, 0, stream>>>(h2, attS2, attD2, as2, ad2, N);
  att_dot<OUTF><<<gW, 256, 0, stream>>>(h3, attS3, attD3, as3, ad3, N);
  aggr_l2_fused<<<gW, 256, 0, stream>>>(rp1, col1, as2, ad2, h2, b2, x1, pred, N);
  aggr_l2_fused<<<gW, 256, 0, stream>>>(rp2, col2, as3, ad3, h3, b3, x2, nullptr, N);
}

// Round 9
// 3970.224 us; speedup vs baseline: 1.0062x; 1.0062x over previous
//
#include <hip/hip_runtime.h>
#include <hip/hip_bf16.h>
#include <math.h>

#define N_NODES 50000
#define E_EDGES 1600000
#define EP_EDGES (E_EDGES + N_NODES)
#define IN_F 512
#define HID 256
#define HEADS 8
#define OUTF 128

typedef unsigned short u16;
typedef __attribute__((ext_vector_type(8))) short short8;
typedef __attribute__((ext_vector_type(4))) float floatx4;

static __device__ __forceinline__ float eluf(float x) {
  return x > 0.f ? x : expm1f(x);
}

static __device__ __forceinline__ u16 bf16_hi(float v) {
  __hip_bfloat16 h = __float2bfloat16(v);
  return *(u16*)&h;
}
static __device__ __forceinline__ float bf16_f(u16 u) {
  __hip_bfloat16 h = *(__hip_bfloat16*)&u;
  return __bfloat162float(h);
}
// 3-way split: v ~= h + m + l, each bf16 (~24 mantissa bits total)
static __device__ __forceinline__ void split3_bf16(float v, u16& h, u16& m, u16& l) {
  h = bf16_hi(v);
  float r1 = v - bf16_f(h);
  m = bf16_hi(r1);
  float r2 = r1 - bf16_f(m);
  l = bf16_hi(r2);
}

// clamp index to [0, n)
static __device__ __forceinline__ int clampi(int v, int n) {
  return v < 0 ? 0 : (v >= n ? n - 1 : v);
}

// ---------------- CSR build ----------------

__global__ void k_detect(const int* __restrict__ ei, int* __restrict__ flag) {
  __shared__ int nz;
  if (threadIdx.x == 0) nz = 0;
  __syncthreads();
  for (int i = threadIdx.x; i < 4096; i += blockDim.x)
    if (ei[2 * i + 1] != 0) nz = 1;   // benign race
  __syncthreads();
  if (threadIdx.x == 0) *flag = (nz ? 0 : 1);
}

__global__ void k_init_deg(int* __restrict__ deg, int n) {
  int i = blockIdx.x * 256 + threadIdx.x;
  if (i < n) deg[i] = 1;   // self loop
}

__global__ void k_count(const int* __restrict__ ei, const int* __restrict__ flag,
                        int* __restrict__ deg, int E) {
  int e = blockIdx.x * 256 + threadIdx.x;
  if (e >= E) return;
  int f = *flag;
  int idx = E + e;                       // row 1 = dst
  int dst = clampi(ei[f ? 2 * idx : idx], N_NODES);
  atomicAdd(&deg[dst], 1);
}

// wave-shfl based scan: inclusive scan of deg -> rp[1..n], rp[0]=0.
__global__ __launch_bounds__(1024) void k_scan(const int* __restrict__ deg,
                                               int* __restrict__ rp, int n) {
  __shared__ int sw[16];
  __shared__ int s_run;
  int tid = threadIdx.x, lane = tid & 63, w = tid >> 6;
  if (tid == 0) s_run = 0;
  __syncthreads();
  for (int base = 0; base < n; base += 1024) {
    int i = base + tid;
    int v = (i < n) ? deg[i] : 0;
    int sv = v;
#pragma unroll
    for (int off = 1; off < 64; off <<= 1) {
      int t = __shfl_up(sv, off);
      if (lane >= off) sv += t;
    }
    if (lane == 63) sw[w] = sv;
    __syncthreads();
    if (w == 0) {
      int wsum = (lane < 16) ? sw[lane] : 0;
#pragma unroll
      for (int off = 1; off < 16; off <<= 1) {
        int t = __shfl_up(wsum, off);
        if (lane >= off) wsum += t;
      }
      if (lane < 16) sw[lane] = wsum;
    }
    __syncthreads();
    int woff = (w > 0) ? sw[w - 1] : 0;
    int run = s_run;
    if (i < n) rp[i + 1] = run + woff + sv;
    __syncthreads();
    if (tid == 1023) s_run = run + sw[15];
    __syncthreads();
  }
  if (tid == 0) rp[0] = 0;
}

__global__ void k_fill_self(const int* __restrict__ rp, int* __restrict__ wp,
                            int* __restrict__ col, int n) {
  int i = blockIdx.x * 256 + threadIdx.x;
  if (i < n) { int p = rp[i]; col[p] = i; wp[i] = p + 1; }
}

__global__ void k_fill_edges(const int* __restrict__ ei, const int* __restrict__ flag,
                             int* __restrict__ wp, int* __restrict__ col, int E) {
  int e = blockIdx.x * 256 + threadIdx.x;
  if (e >= E) return;
  int f = *flag;
  int src = clampi(ei[f ? 2 * e : e], N_NODES);
  int didx = E + e;
  int dst = clampi(ei[f ? 2 * didx : didx], N_NODES);
  int p = atomicAdd(&wp[dst], 1);
  col[p] = src;
}

// ---------------- weight transpose + 3-way split ----------------
__global__ void k_split3_t(const float* __restrict__ W, u16* __restrict__ H,
                           u16* __restrict__ Mv, u16* __restrict__ L,
                           int kshift, int kmask, int Nw, int total) {
  int idx = blockIdx.x * 256 + threadIdx.x;
  if (idx >= total) return;
  int n = idx >> kshift;
  int k = idx & kmask;
  u16 h, m, l;
  split3_bf16(W[(size_t)k * Nw + n], h, m, l);
  H[idx] = h;
  Mv[idx] = m;
  L[idx] = l;
}

// ---------------- attention projection: w_att = W1_h @ att ----------------
__global__ __launch_bounds__(256) void k_watt1(
    const float* __restrict__ W1, const float* __restrict__ attS,
    const float* __restrict__ attD, float* __restrict__ watt) {
  int wid = (blockIdx.x * 256 + threadIdx.x) >> 6;   // one wave per (k,h)
  int lane = threadIdx.x & 63;
  if (wid >= IN_F * HEADS) return;
  int k = wid >> 3, h = wid & 7;
  float4 wv = *(const float4*)&W1[(size_t)k * (HID * HEADS) + h * HID + lane * 4];
  float4 sv = *(const float4*)&attS[h * HID + lane * 4];
  float4 dv = *(const float4*)&attD[h * HID + lane * 4];
  float s = wv.x * sv.x + wv.y * sv.y + wv.z * sv.z + wv.w * sv.w;
  float d = wv.x * dv.x + wv.y * dv.y + wv.z * dv.z + wv.w * dv.w;
  for (int off = 32; off; off >>= 1) {
    s += __shfl_xor(s, off);
    d += __shfl_xor(d, off);
  }
  if (lane == 0) {
    watt[(size_t)(2 * h) * IN_F + k] = s;
    watt[(size_t)(2 * h + 1) * IN_F + k] = d;
  }
}

// a_src/a_dst for ALL heads in one pass over x.
__global__ __launch_bounds__(256) void k_asad1(
    const float* __restrict__ x, const float* __restrict__ watt,
    float* __restrict__ asall, float* __restrict__ adall, int n) {
  int node = (blockIdx.x * 256 + threadIdx.x) >> 6;
  int lane = threadIdx.x & 63;
  if (node >= n) return;
  float4 x0 = *(const float4*)&x[(size_t)node * IN_F + lane * 8];
  float4 x1 = *(const float4*)&x[(size_t)node * IN_F + lane * 8 + 4];
  for (int h = 0; h < HEADS; ++h) {
    const float* ws = watt + (size_t)(2 * h) * IN_F + lane * 8;
    const float* wd = watt + (size_t)(2 * h + 1) * IN_F + lane * 8;
    float4 s0 = *(const float4*)ws, s1 = *(const float4*)(ws + 4);
    float4 d0 = *(const float4*)wd, d1 = *(const float4*)(wd + 4);
    float s = x0.x * s0.x + x0.y * s0.y + x0.z * s0.z + x0.w * s0.w
            + x1.x * s1.x + x1.y * s1.y + x1.z * s1.z + x1.w * s1.w;
    float d = x0.x * d0.x + x0.y * d0.y + x0.z * d0.z + x0.w * d0.w
            + x1.x * d1.x + x1.y * d1.y + x1.z * d1.z + x1.w * d1.w;
    for (int off = 32; off; off >>= 1) {
      s += __shfl_xor(s, off);
      d += __shfl_xor(d, off);
    }
    if (lane == 0) {
      asall[(size_t)h * n + node] = s;
      adall[(size_t)h * n + node] = d;
    }
  }
}

// ---------------- split-bf16 MFMA GEMM machinery ----------------
#define GBM 128
#define GBN 128
#define GBK 32
#define GM1 391   // ceil(50000/128)

#define MFMA_BF16 __builtin_amdgcn_mfma_f32_16x16x32_bf16

__device__ __forceinline__ void gemm_epilogue(floatx4 acc[4][4], float* C,
                                              int ldc, int M, int accum,
                                              int row0, int col0, int wr,
                                              int wc, int lane) {
  int q = lane >> 4, n15 = lane & 15;
#pragma unroll
  for (int i = 0; i < 4; ++i) {
#pragma unroll
    for (int r = 0; r < 4; ++r) {
      int row = row0 + wr * 64 + i * 16 + q * 4 + r;
      if (row < M) {
#pragma unroll
        for (int j = 0; j < 4; ++j) {
          int cg = col0 + wc * 64 + j * 16 + n15;
          float v = acc[i][j][r];
          if (accum) v += C[(size_t)row * ldc + cg];
          C[(size_t)row * ldc + cg] = v;
        }
      }
    }
  }
}

// GEMM1 core: A = x (fp32, split 3-way on the fly), B pre-split 3-way.
__device__ __forceinline__ void gemm1_core(
    const float* __restrict__ X, int lda,
    const u16* __restrict__ Bh, const u16* __restrict__ Bm,
    const u16* __restrict__ Bl, int ldb,
    float* __restrict__ C, int ldc, int M, int K, int row0, int col0,
    u16* lds) {
  int tid = threadIdx.x;
  int lane = tid & 63, wave = tid >> 6;
  int wr = wave >> 1, wc = wave & 1;
  floatx4 acc[4][4] = {};
  int m0 = tid >> 2, m1 = (tid + 256) >> 2;
  int q0 = tid & 3;
  int lo0 = ((m0 >> 4) * 64 + q0 * 16 + (m0 & 15)) * 8;
  int lo1 = ((m1 >> 4) * 64 + q0 * 16 + (m1 & 15)) * 8;

  for (int k0 = 0; k0 < K; k0 += GBK) {
#pragma unroll
    for (int c = 0; c < 2; ++c) {
      int m = c ? m1 : m0;
      int lo = c ? lo1 : lo0;
      int gr = row0 + m;
      float f[8];
      if (gr < M) {
        float4 f0 = *(const float4*)(X + (size_t)gr * lda + k0 + q0 * 8);
        float4 f1 = *(const float4*)(X + (size_t)gr * lda + k0 + q0 * 8 + 4);
        f[0] = f0.x; f[1] = f0.y; f[2] = f0.z; f[3] = f0.w;
        f[4] = f1.x; f[5] = f1.y; f[6] = f1.z; f[7] = f1.w;
      } else {
#pragma unroll
        for (int e = 0; e < 8; ++e) f[e] = 0.f;
      }
      short8 vh, vm, vl;
#pragma unroll
      for (int e = 0; e < 8; ++e) {
        u16 h, m2, l;
        split3_bf16(f[e], h, m2, l);
        vh[e] = (short)h; vm[e] = (short)m2; vl[e] = (short)l;
      }
      *(short8*)&lds[lo] = vh;
      *(short8*)&lds[4096 + lo] = vm;
      *(short8*)&lds[8192 + lo] = vl;
    }
#pragma unroll
    for (int c = 0; c < 2; ++c) {
      int m = c ? m1 : m0;
      int lo = c ? lo1 : lo0;
      size_t go = (size_t)(col0 + m) * ldb + k0 + q0 * 8;
      *(short8*)&lds[12288 + lo] = *(const short8*)(Bh + go);
      *(short8*)&lds[16384 + lo] = *(const short8*)(Bm + go);
      *(short8*)&lds[20480 + lo] = *(const short8*)(Bl + go);
    }
    __syncthreads();
    short8 a_h[4], a_m[4], a_l[4];
#pragma unroll
    for (int i = 0; i < 4; ++i) {
      int o = ((wr * 4 + i) * 64 + lane) * 8;
      a_h[i] = *(short8*)&lds[o];
      a_m[i] = *(short8*)&lds[4096 + o];
      a_l[i] = *(short8*)&lds[8192 + o];
    }
#pragma unroll
    for (int j = 0; j < 4; ++j) {
      int o = ((wc * 4 + j) * 64 + lane) * 8;
      short8 b_h = *(short8*)&lds[12288 + o];
      short8 b_m = *(short8*)&lds[16384 + o];
      short8 b_l = *(short8*)&lds[20480 + o];
#pragma unroll
      for (int i = 0; i < 4; ++i) {
        acc[i][j] = MFMA_BF16(a_l[i], b_h, acc[i][j], 0, 0, 0);
        acc[i][j] = MFMA_BF16(a_m[i], b_m, acc[i][j], 0, 0, 0);
        acc[i][j] = MFMA_BF16(a_h[i], b_l, acc[i][j], 0, 0, 0);
        acc[i][j] = MFMA_BF16(a_m[i], b_h, acc[i][j], 0, 0, 0);
        acc[i][j] = MFMA_BF16(a_h[i], b_m, acc[i][j], 0, 0, 0);
        acc[i][j] = MFMA_BF16(a_h[i], b_h, acc[i][j], 0, 0, 0);
      }
    }
    __syncthreads();
  }
  gemm_epilogue(acc, C, ldc, M, 0, row0, col0, wr, wc, lane);
}

__global__ __launch_bounds__(256) void gemm1_k(
    const float* __restrict__ X, int lda,
    const u16* __restrict__ Bh, const u16* __restrict__ Bm,
    const u16* __restrict__ Bl, int ldb,
    float* __restrict__ C, int ldc, int M, int K) {
  __shared__ __align__(16) u16 lds[24576];
  gemm1_core(X, lda, Bh, Bm, Bl, ldb, C, ldc, M, K,
             blockIdx.x * GBM, blockIdx.y * GBN, lds);
}

// prologue: gemm1(head0) tiles || CSR-2 degree count (independent roles).
// Grid is EXACTLY nG + ceil(E2/256): no rounding overflow blocks.
__global__ __launch_bounds__(256) void prologue_k(
    const float* __restrict__ X,
    const u16* __restrict__ Bh, const u16* __restrict__ Bm,
    const u16* __restrict__ Bl, float* __restrict__ C, int M,
    const int* __restrict__ ei2, const int* __restrict__ flag,
    int* __restrict__ deg2, int E2, int nG) {
  __shared__ __align__(16) u16 lds[24576];
  int b = blockIdx.x;
  if (b < nG) {
    int bx = b % GM1, by = b / GM1;
    gemm1_core(X, IN_F, Bh, Bm, Bl, IN_F, C, HID, M, IN_F,
               bx * GBM, by * GBN, lds);
    return;
  }
  int e = (b - nG) * 256 + threadIdx.x;
  if (e >= E2) return;
  int f = *flag;
  int idx = E2 + e;                      // row 1 = dst
  int dst = clampi(ei2[f ? 2 * idx : idx], N_NODES);
  atomicAdd(&deg2[dst], 1);
}

// 6-term core with pre-split A (used for h2). accum flag.
__device__ __forceinline__ void gemm_core6(
    const u16* __restrict__ Ah, const u16* __restrict__ Am,
    const u16* __restrict__ Al, int lda,
    const u16* __restrict__ Bh, const u16* __restrict__ Bm,
    const u16* __restrict__ Bl, int ldb,
    float* __restrict__ C, int ldc, int M, int K, int row0, int col0,
    int accum, u16* lds) {
  int tid = threadIdx.x;
  int lane = tid & 63, wave = tid >> 6;
  int wr = wave >> 1, wc = wave & 1;
  floatx4 acc[4][4] = {};
  int m0 = tid >> 2, m1 = (tid + 256) >> 2;
  int q0 = tid & 3;
  int lo0 = ((m0 >> 4) * 64 + q0 * 16 + (m0 & 15)) * 8;
  int lo1 = ((m1 >> 4) * 64 + q0 * 16 + (m1 & 15)) * 8;
  for (int k0 = 0; k0 < K; k0 += GBK) {
#pragma unroll
    for (int c = 0; c < 2; ++c) {
      int m = c ? m1 : m0;
      int lo = c ? lo1 : lo0;
      int gr = row0 + m;
      short8 vh = {}, vm = {}, vl = {};
      if (gr < M) {
        size_t go = (size_t)gr * lda + k0 + q0 * 8;
        vh = *(const short8*)(Ah + go);
        vm = *(const short8*)(Am + go);
        vl = *(const short8*)(Al + go);
      }
      *(short8*)&lds[lo] = vh;
      *(short8*)&lds[4096 + lo] = vm;
      *(short8*)&lds[8192 + lo] = vl;
      size_t go = (size_t)(col0 + m) * ldb + k0 + q0 * 8;
      *(short8*)&lds[12288 + lo] = *(const short8*)(Bh + go);
      *(short8*)&lds[16384 + lo] = *(const short8*)(Bm + go);
      *(short8*)&lds[20480 + lo] = *(const short8*)(Bl + go);
    }
    __syncthreads();
    short8 a_h[4], a_m[4], a_l[4];
#pragma unroll
    for (int i = 0; i < 4; ++i) {
      int o = ((wr * 4 + i) * 64 + lane) * 8;
      a_h[i] = *(short8*)&lds[o];
      a_m[i] = *(short8*)&lds[4096 + o];
      a_l[i] = *(short8*)&lds[8192 + o];
    }
#pragma unroll
    for (int j = 0; j < 4; ++j) {
      int o = ((wc * 4 + j) * 64 + lane) * 8;
      short8 b_h = *(short8*)&lds[12288 + o];
      short8 b_m = *(short8*)&lds[16384 + o];
      short8 b_l = *(short8*)&lds[20480 + o];
#pragma unroll
      for (int i = 0; i < 4; ++i) {
        acc[i][j] = MFMA_BF16(a_l[i], b_h, acc[i][j], 0, 0, 0);
        acc[i][j] = MFMA_BF16(a_m[i], b_m, acc[i][j], 0, 0, 0);
        acc[i][j] = MFMA_BF16(a_h[i], b_l, acc[i][j], 0, 0, 0);
        acc[i][j] = MFMA_BF16(a_m[i], b_h, acc[i][j], 0, 0, 0);
        acc[i][j] = MFMA_BF16(a_h[i], b_m, acc[i][j], 0, 0, 0);
        acc[i][j] = MFMA_BF16(a_h[i], b_h, acc[i][j], 0, 0, 0);
      }
    }
    __syncthreads();
  }
  gemm_epilogue(acc, C, ldc, M, accum, row0, col0, wr, wc, lane);
}

// 3-term (2-way split) core — used for h3. accum flag.
__device__ __forceinline__ void gemm_core3(
    const u16* __restrict__ Ah, const u16* __restrict__ Am, int lda,
    const u16* __restrict__ Bh, const u16* __restrict__ Bm, int ldb,
    float* __restrict__ C, int ldc, int M, int K, int row0, int col0,
    int accum, u16* lds) {
  int tid = threadIdx.x;
  int lane = tid & 63, wave = tid >> 6;
  int wr = wave >> 1, wc = wave & 1;
  floatx4 acc[4][4] = {};
  int m0 = tid >> 2, m1 = (tid + 256) >> 2;
  int q0 = tid & 3;
  int lo0 = ((m0 >> 4) * 64 + q0 * 16 + (m0 & 15)) * 8;
  int lo1 = ((m1 >> 4) * 64 + q0 * 16 + (m1 & 15)) * 8;
  for (int k0 = 0; k0 < K; k0 += GBK) {
#pragma unroll
    for (int c = 0; c < 2; ++c) {
      int m = c ? m1 : m0;
      int lo = c ? lo1 : lo0;
      int gr = row0 + m;
      short8 vh = {}, vm = {};
      if (gr < M) {
        size_t go = (size_t)gr * lda + k0 + q0 * 8;
        vh = *(const short8*)(Ah + go);
        vm = *(const short8*)(Am + go);
      }
      *(short8*)&lds[lo] = vh;
      *(short8*)&lds[4096 + lo] = vm;
      size_t go = (size_t)(col0 + m) * ldb + k0 + q0 * 8;
      *(short8*)&lds[12288 + lo] = *(const short8*)(Bh + go);
      *(short8*)&lds[16384 + lo] = *(const short8*)(Bm + go);
    }
    __syncthreads();
    short8 a_h[4], a_m[4];
#pragma unroll
    for (int i = 0; i < 4; ++i) {
      int o = ((wr * 4 + i) * 64 + lane) * 8;
      a_h[i] = *(short8*)&lds[o];
      a_m[i] = *(short8*)&lds[4096 + o];
    }
#pragma unroll
    for (int j = 0; j < 4; ++j) {
      int o = ((wc * 4 + j) * 64 + lane) * 8;
      short8 b_h = *(short8*)&lds[12288 + o];
      short8 b_m = *(short8*)&lds[16384 + o];
#pragma unroll
      for (int i = 0; i < 4; ++i) {
        acc[i][j] = MFMA_BF16(a_m[i], b_h, acc[i][j], 0, 0, 0);
        acc[i][j] = MFMA_BF16(a_h[i], b_m, acc[i][j], 0, 0, 0);
        acc[i][j] = MFMA_BF16(a_h[i], b_h, acc[i][j], 0, 0, 0);
      }
    }
    __syncthreads();
  }
  gemm_epilogue(acc, C, ldc, M, accum, row0, col0, wr, wc, lane);
}

// standalone GEMM2/3 (used for the final head and the fallback path)
__global__ __launch_bounds__(256) void gemm23_k(
    const u16* __restrict__ Ah, const u16* __restrict__ Am,
    const u16* __restrict__ Al, int lda,
    const u16* __restrict__ B2h, const u16* __restrict__ B2m,
    const u16* __restrict__ B2l,
    const u16* __restrict__ B3h, const u16* __restrict__ B3m, int ldb,
    float* __restrict__ C2, float* __restrict__ C3, int ldc, int M, int K,
    int accum) {
  __shared__ __align__(16) u16 lds[24576];
  if (blockIdx.z == 0)
    gemm_core6(Ah, Am, Al, lda, B2h, B2m, B2l, ldb, C2, ldc, M, K,
               blockIdx.x * GBM, 0, accum, lds);
  else
    gemm_core3(Ah, Am, lda, B3h, B3m, ldb, C3, ldc, M, K,
               blockIdx.x * GBM, 0, accum, lds);
}

// ---------------- attention dot products (layer 2, both h2/h3) -----------
__global__ __launch_bounds__(256) void att_dot_dual(
    const float* __restrict__ h2, const float* __restrict__ h3,
    const float* __restrict__ s2, const float* __restrict__ d2,
    const float* __restrict__ s3, const float* __restrict__ d3,
    float* __restrict__ as2, float* __restrict__ ad2,
    float* __restrict__ as3, float* __restrict__ ad3, int n, int gW) {
  int b = blockIdx.x;
  int second = (b >= gW) ? 1 : 0;
  int bb = second ? b - gW : b;
  const float* h  = second ? h3 : h2;
  const float* sS = second ? s3 : s2;
  const float* sD = second ? d3 : d2;
  float* oS = second ? as3 : as2;
  float* oD = second ? ad3 : ad2;
  int node = (bb * 256 + threadIdx.x) >> 6;
  int lane = threadIdx.x & 63;
  if (node >= n) return;
  float2 hv = *(const float2*)&h[(size_t)node * OUTF + lane * 2];
  float2 sv = *(const float2*)&sS[lane * 2];
  float2 dv = *(const float2*)&sD[lane * 2];
  float s = hv.x * sv.x + hv.y * sv.y;
  float d = hv.x * dv.x + hv.y * dv.y;
  for (int off = 32; off; off >>= 1) {
    s += __shfl_xor(s, off);
    d += __shfl_xor(d, off);
  }
  if (lane == 0) { oS[node] = s; oD[node] = d; }
}

// ---------------- layer-1 fused softmax + gather-aggregate core -----------
// 8 rows in flight per wave (measured-best depth).
static __device__ __forceinline__ void aggr_l1_core(
    int node, int lane,
    const int* __restrict__ rp, const int* __restrict__ col,
    const float* __restrict__ aS, const float* __restrict__ aD,
    const float* __restrict__ h, const float* __restrict__ bias,
    u16* __restrict__ embH, u16* __restrict__ embM, u16* __restrict__ embL,
    int ecol0, int ldE, int n) {
  int s0 = rp[node], s1 = rp[node + 1];
  int d = s1 - s0;
  float ad = aD[node];
  float4 acc = make_float4(0.f, 0.f, 0.f, 0.f);

  if (d <= 64) {
    int c = 0;
    float e = -3.0e38f;
    if (lane < d) {
      c = clampi(col[s0 + lane], n);
      float t = aS[c] + ad;
      e = t >= 0.f ? t : 0.2f * t;
    }
    float m = e;
    for (int off = 32; off; off >>= 1) m = fmaxf(m, __shfl_xor(m, off));
    float ex = (lane < d) ? expf(e - m) : 0.f;
    float s = ex;
    for (int off = 32; off; off >>= 1) s += __shfl_xor(s, off);
    float al = ex * (1.f / (s + 1e-16f));   // 0 for lanes >= d
    int d8 = d & ~7;
    for (int j = 0; j < d8; j += 8) {
#pragma unroll
      for (int t = 0; t < 8; ++t) {
        int ct = __shfl(c, j + t);
        float at = __shfl(al, j + t);
        float4 hv = *(const float4*)&h[(size_t)ct * HID + lane * 4];
        acc.x += at * hv.x; acc.y += at * hv.y;
        acc.z += at * hv.z; acc.w += at * hv.w;
      }
    }
    if (d8 < d) {
#pragma unroll
      for (int t = 0; t < 8; ++t) {
        if (d8 + t < d) {    // wave-uniform branch (d is per-wave scalar)
          int ct = __shfl(c, d8 + t);
          float at = __shfl(al, d8 + t);
          float4 hv = *(const float4*)&h[(size_t)ct * HID + lane * 4];
          acc.x += at * hv.x; acc.y += at * hv.y;
          acc.z += at * hv.z; acc.w += at * hv.w;
        }
      }
    }
  } else {
    float m = -3.0e38f;
    for (int i = s0 + lane; i < s1; i += 64) {
      float e = aS[clampi(col[i], n)] + ad;
      e = e >= 0.f ? e : 0.2f * e;
      m = fmaxf(m, e);
    }
    for (int off = 32; off; off >>= 1) m = fmaxf(m, __shfl_xor(m, off));
    float sum = 0.f;
    for (int i = s0 + lane; i < s1; i += 64) {
      float e = aS[clampi(col[i], n)] + ad;
      e = e >= 0.f ? e : 0.2f * e;
      sum += expf(e - m);
    }
    for (int off = 32; off; off >>= 1) sum += __shfl_xor(sum, off);
    float inv = 1.f / (sum + 1e-16f);
    for (int i = s0; i < s1; ++i) {
      int ci = clampi(col[i], n);
      float e = aS[ci] + ad;
      e = e >= 0.f ? e : 0.2f * e;
      float a = expf(e - m) * inv;
      float4 hv = *(const float4*)&h[(size_t)ci * HID + lane * 4];
      acc.x += a * hv.x; acc.y += a * hv.y; acc.z += a * hv.z; acc.w += a * hv.w;
    }
  }

  float4 bb = *(const float4*)&bias[lane * 4];
  float v0 = eluf(acc.x + bb.x);
  float v1 = eluf(acc.y + bb.y);
  float v2 = eluf(acc.z + bb.z);
  float v3 = eluf(acc.w + bb.w);
  ushort4 uh, um, ul;
  split3_bf16(v0, uh.x, um.x, ul.x);
  split3_bf16(v1, uh.y, um.y, ul.y);
  split3_bf16(v2, uh.z, um.z, ul.z);
  split3_bf16(v3, uh.w, um.w, ul.w);
  size_t o = (size_t)node * ldE + ecol0 + lane * 4;
  *(ushort4*)&embH[o] = uh;
  *(ushort4*)&embM[o] = um;
  *(ushort4*)&embL[o] = ul;
}

__global__ __launch_bounds__(256) void aggr_l1_fused(
    const int* __restrict__ rp, const int* __restrict__ col,
    const float* __restrict__ aS, const float* __restrict__ aD,
    const float* __restrict__ h, const float* __restrict__ bias,
    u16* __restrict__ embH, u16* __restrict__ embM, u16* __restrict__ embL,
    int ecol0, int ldE, int n) {
  int node = (blockIdx.x * 256 + threadIdx.x) >> 6;
  int lane = threadIdx.x & 63;
  if (node >= n) return;
  aggr_l1_core(node, lane, rp, col, aS, aD, h, bias, embH, embM, embL,
               ecol0, ldE, n);
}

// ---------------- fused pipeline step ----------------
// Roles: A (bulk) aggr(h); B gemm1(h+1) (nG1); C gemm23(h-1) (nG23);
// E (step 0 only) CSR-2 fill_edges (nE blocks after the aggr range).
// NOTE: role-E blocks are guarded by eb < nE — grid-rounding overflow
// blocks (from the 9*nC stripe rule) must be inert, not edge-fillers.
__global__ __launch_bounds__(256) void fused_step(
    // role A
    const int* __restrict__ rp, const int* __restrict__ col,
    const float* __restrict__ aS, const float* __restrict__ aD,
    const float* __restrict__ hg, const float* __restrict__ bias,
    u16* __restrict__ embH, u16* __restrict__ embM, u16* __restrict__ embL,
    int ecol0, int ldE, int n,
    // role B
    const float* __restrict__ X,
    const u16* __restrict__ B1h, const u16* __restrict__ B1m,
    const u16* __restrict__ B1l, float* __restrict__ h1out, int nG1,
    // role C
    const u16* __restrict__ A23h, const u16* __restrict__ A23m,
    const u16* __restrict__ A23l,
    const u16* __restrict__ B2h, const u16* __restrict__ B2m,
    const u16* __restrict__ B2l,
    const u16* __restrict__ B3h, const u16* __restrict__ B3m,
    float* __restrict__ C2, float* __restrict__ C3, int accum, int nG23,
    // role E (CSR-2 edge fill; nE=0 except step 0)
    const int* __restrict__ ei2, const int* __restrict__ flag,
    int* __restrict__ wp2, int* __restrict__ col2, int nE, int E2) {
  __shared__ __align__(16) u16 lds[24576];
  int nC = nG1 + nG23;
  int k = blockIdx.x;
  int q = k / 9, r = k - q * 9;
  if (r == 0 && q < nC) {
    if (q < nG1) {
      int bx = q % GM1, by = q / GM1;
      gemm1_core(X, IN_F, B1h, B1m, B1l, IN_F, h1out, HID, n, IN_F,
                 bx * GBM, by * GBN, lds);
    } else {
      int p = q - nG1;
      int z = p / GM1, bx = p - z * GM1;
      if (z == 0)
        gemm_core6(A23h, A23m, A23l, ldE, B2h, B2m, B2l, HID * HEADS,
                   C2, OUTF, n, HID, bx * GBM, 0, accum, lds);
      else
        gemm_core3(A23h, A23m, ldE, B3h, B3m, HID * HEADS,
                   C3, OUTF, n, HID, bx * GBM, 0, accum, lds);
    }
    return;
  }
  int skipped = q + (r ? 1 : 0);
  if (skipped > nC) skipped = nC;
  int aggrIdx = k - skipped;
  int nb = (n + 3) >> 2;             // aggr blocks (4 nodes/block)
  if (aggrIdx < nb) {
    int node = aggrIdx * 4 + (threadIdx.x >> 6);
    int lane = threadIdx.x & 63;
    if (node >= n) return;
    aggr_l1_core(node, lane, rp, col, aS, aD, hg, bias, embH, embM, embL,
                 ecol0, ldE, n);
    return;
  }
  // role E: CSR-2 fill_edges — ONLY the nE blocks allocated for it.
  int eb = aggrIdx - nb;
  if (eb >= nE) return;              // inert overflow blocks (bug fix)
  int e = eb * 256 + (int)threadIdx.x;
  if (e >= E2) return;
  int f = *flag;
  int src = clampi(ei2[f ? 2 * e : e], N_NODES);
  int didx = E2 + e;
  int dst = clampi(ei2[f ? 2 * didx : didx], N_NODES);
  int p = atomicAdd(&wp2[dst], 1);
  col2[p] = src;
}

// ---------------- layer-2 dual: softmax + gather + row-softmax ------------
// Blocks [0,gW) -> x1 (graph1/h2, with predictions); [gW,2gW) -> x2.
__global__ __launch_bounds__(256) void aggr_l2_dual(
    const int* __restrict__ rp1, const int* __restrict__ col1,
    const float* __restrict__ as2, const float* __restrict__ ad2,
    const float* __restrict__ h2, const float* __restrict__ b2,
    float* __restrict__ x1, float* __restrict__ pred,
    const int* __restrict__ rp2, const int* __restrict__ col2,
    const float* __restrict__ as3, const float* __restrict__ ad3,
    const float* __restrict__ h3, const float* __restrict__ b3,
    float* __restrict__ x2, int n, int gW) {
  int b = blockIdx.x;
  int second = (b >= gW) ? 1 : 0;
  int bb = second ? b - gW : b;
  const int* rp = second ? rp2 : rp1;
  const int* col = second ? col2 : col1;
  const float* aS = second ? as3 : as2;
  const float* aD = second ? ad3 : ad2;
  const float* h = second ? h3 : h2;
  const float* bias = second ? b3 : b2;
  float* out = second ? x2 : x1;
  float* pr = second ? nullptr : pred;

  int node = (bb * 256 + threadIdx.x) >> 6;
  int lane = threadIdx.x & 63;
  if (node >= n) return;
  int s0 = rp[node], s1 = rp[node + 1];
  int d = s1 - s0;
  float ad = aD[node];
  float2 acc = make_float2(0.f, 0.f);

  if (d <= 64) {
    int c = 0;
    float e = -3.0e38f;
    if (lane < d) {
      c = clampi(col[s0 + lane], n);
      float t = aS[c] + ad;
      e = t >= 0.f ? t : 0.2f * t;
    }
    float m = e;
    for (int off = 32; off; off >>= 1) m = fmaxf(m, __shfl_xor(m, off));
    float ex = (lane < d) ? expf(e - m) : 0.f;
    float s = ex;
    for (int off = 32; off; off >>= 1) s += __shfl_xor(s, off);
    float al = ex * (1.f / (s + 1e-16f));
    int d8 = d & ~7;
    for (int j = 0; j < d8; j += 8) {
#pragma unroll
      for (int t = 0; t < 8; ++t) {
        int ct = __shfl(c, j + t);
        float at = __shfl(al, j + t);
        float2 hv = *(const float2*)&h[(size_t)ct * OUTF + lane * 2];
        acc.x += at * hv.x; acc.y += at * hv.y;
      }
    }
    if (d8 < d) {
#pragma unroll
      for (int t = 0; t < 8; ++t) {
        if (d8 + t < d) {   // wave-uniform
          int ct = __shfl(c, d8 + t);
          float at = __shfl(al, d8 + t);
          float2 hv = *(const float2*)&h[(size_t)ct * OUTF + lane * 2];
          acc.x += at * hv.x; acc.y += at * hv.y;
        }
      }
    }
  } else {
    float m = -3.0e38f;
    for (int i = s0 + lane; i < s1; i += 64) {
      float e = aS[clampi(col[i], n)] + ad;
      e = e >= 0.f ? e : 0.2f * e;
      m = fmaxf(m, e);
    }
    for (int off = 32; off; off >>= 1) m = fmaxf(m, __shfl_xor(m, off));
    float sum = 0.f;
    for (int i = s0 + lane; i < s1; i += 64) {
      float e = aS[clampi(col[i], n)] + ad;
      e = e >= 0.f ? e : 0.2f * e;
      sum += expf(e - m);
    }
    for (int off = 32; off; off >>= 1) sum += __shfl_xor(sum, off);
    float inv = 1.f / (sum + 1e-16f);
    for (int i = s0; i < s1; ++i) {
      int ci = clampi(col[i], n);
      float e = aS[ci] + ad;
      e = e >= 0.f ? e : 0.2f * e;
      float a = expf(e - m) * inv;
      float2 hv = *(const float2*)&h[(size_t)ci * OUTF + lane * 2];
      acc.x += a * hv.x; acc.y += a * hv.y;
    }
  }

  float2 bb2 = *(const float2*)&bias[lane * 2];
  acc.x += bb2.x; acc.y += bb2.y;

  // ---- fused row softmax + argmax ----
  float bv;
  int bi;
  if (acc.y > acc.x) { bv = acc.y; bi = 2 * lane + 1; }
  else               { bv = acc.x; bi = 2 * lane; }
  for (int off = 32; off; off >>= 1) {
    float ov = __shfl_xor(bv, off);
    int oi = __shfl_xor(bi, off);
    if (ov > bv || (ov == bv && oi < bi)) { bv = ov; bi = oi; }
  }
  float e0 = expf(acc.x - bv), e1 = expf(acc.y - bv);
  float ssum = e0 + e1;
  for (int off = 32; off; off >>= 1) ssum += __shfl_xor(ssum, off);
  float2 r;
  r.x = e0 / ssum;
  r.y = e1 / ssum;
  *(float2*)&out[(size_t)node * OUTF + lane * 2] = r;
  if (pr != nullptr && lane == 0) pr[node] = (float)bi;
}

// ---------------- host orchestration ----------------
extern "C" void kernel_launch(void* const* d_in, const int* in_sizes, int n_in,
                              void* d_out, int out_size, void* d_ws, size_t ws_size,
                              hipStream_t stream) {
  const int N = N_NODES, E = E_EDGES;
  const float* x     = (const float*)d_in[0];
  const int*   ei1   = (const int*)d_in[1];
  const int*   ei2   = (const int*)d_in[2];
  const float* W1    = (const float*)d_in[3];
  const float* attS1 = (const float*)d_in[4];
  const float* attD1 = (const float*)d_in[5];
  const float* b1    = (const float*)d_in[6];
  const float* W2    = (const float*)d_in[7];
  const float* attS2 = (const float*)d_in[8];
  const float* attD2 = (const float*)d_in[9];
  const float* b2    = (const float*)d_in[10];
  const float* W3    = (const float*)d_in[11];
  const float* attS3 = (const float*)d_in[12];
  const float* attD3 = (const float*)d_in[13];
  const float* b3    = (const float*)d_in[14];

  // ---- decide pipelined vs fallback by workspace size ----
  size_t needPipe =
      2 * ((size_t)EP_EDGES * 4) + 2 * ((size_t)(N + 1) * 4) +
      2 * ((size_t)N * 4) + 4096 +
      2 * ((size_t)N * HID * 4) +                      // h1h x2
      3 * ((size_t)N * 512 * 2) +                      // emb (2-head wide)
      (size_t)N * OUTF * 4 * 2 +                       // h2+h3
      3 * ((size_t)IN_F * HID * HEADS * 2) +           // W1T
      6 * ((size_t)HID * HEADS * OUTF * 2) +           // W2T/W3T
      2 * ((size_t)HEADS * N * 4) +                    // asall/adall
      4 * ((size_t)N * 4) +                            // as2..ad3
      (size_t)2 * HEADS * IN_F * 4 +                   // watt
      (size_t)(8 << 20);                               // slack
  int pipe = (ws_size >= needPipe) ? 1 : 0;
  const int nbuf = pipe ? 2 : 1;
  const int ldE = pipe ? 512 : 256;

  char* ws = (char*)d_ws;
  size_t off = 0;
  auto take = [&](size_t bytes) {
    off = (off + 255) & ~(size_t)255;
    size_t o = off;
    off += bytes;
    return o;
  };
  int*   col1 = (int*)(ws + take((size_t)EP_EDGES * 4));
  int*   col2 = (int*)(ws + take((size_t)EP_EDGES * 4));
  int*   rp1  = (int*)(ws + take((size_t)(N + 1) * 4));
  int*   rp2  = (int*)(ws + take((size_t)(N + 1) * 4));
  int*   wp1  = (int*)(ws + take((size_t)N * 4));
  int*   wp2  = (int*)(ws + take((size_t)N * 4));
  int*   flag = (int*)(ws + take(256));
  float* h1hA = (float*)(ws + take((size_t)N * HID * 4 * nbuf));
  float* h1hB = pipe ? h1hA + (size_t)N * HID : h1hA;
  u16*   embH = (u16*)(ws + take((size_t)N * ldE * 2));
  u16*   embM = (u16*)(ws + take((size_t)N * ldE * 2));
  u16*   embL = (u16*)(ws + take((size_t)N * ldE * 2));
  float* h2   = (float*)(ws + take((size_t)N * OUTF * 4 * 2));  // h2+h3
  float* h3   = h2 + (size_t)N * OUTF;
  u16*   W1Th = (u16*)(ws + take((size_t)IN_F * HID * HEADS * 2));  // [2048][512]
  u16*   W1Tm = (u16*)(ws + take((size_t)IN_F * HID * HEADS * 2));
  u16*   W1Tl = (u16*)(ws + take((size_t)IN_F * HID * HEADS * 2));
  u16*   W2Th = (u16*)(ws + take((size_t)HID * HEADS * OUTF * 2)); // [128][2048]
  u16*   W2Tm = (u16*)(ws + take((size_t)HID * HEADS * OUTF * 2));
  u16*   W2Tl = (u16*)(ws + take((size_t)HID * HEADS * OUTF * 2));
  u16*   W3Th = (u16*)(ws + take((size_t)HID * HEADS * OUTF * 2));
  u16*   W3Tm = (u16*)(ws + take((size_t)HID * HEADS * OUTF * 2));
  u16*   W3Tl = (u16*)(ws + take((size_t)HID * HEADS * OUTF * 2)); // dummy L
  float* asall = (float*)(ws + take((size_t)HEADS * N * 4));
  float* adall = (float*)(ws + take((size_t)HEADS * N * 4));
  float* as2  = (float*)(ws + take((size_t)N * 4));
  float* ad2  = (float*)(ws + take((size_t)N * 4));
  float* as3  = (float*)(ws + take((size_t)N * 4));
  float* ad3  = (float*)(ws + take((size_t)N * 4));
  float* watt = (float*)(ws + take((size_t)2 * HEADS * IN_F * 4));

  float* outp = (float*)d_out;
  float* x1   = outp;                         // logits   [N,128]
  float* x2   = outp + (size_t)N * OUTF;      // logits_2 [N,128]
  float* pred = outp + (size_t)2 * N * OUTF;  // predictions [N]

  const int gN = (N + 255) / 256;
  const int gE = (E + 255) / 256;               // 6250
  const int gW = (N + 3) / 4;                   // one wave per node = 12500

  // ---- weight transpose + 3-way splits ----
  k_split3_t<<<(IN_F * HID * HEADS + 255) / 256, 256, 0, stream>>>(
      W1, W1Th, W1Tm, W1Tl, 9, 511, HID * HEADS, IN_F * HID * HEADS);
  k_split3_t<<<(HID * HEADS * OUTF + 255) / 256, 256, 0, stream>>>(
      W2, W2Th, W2Tm, W2Tl, 11, 2047, OUTF, HID * HEADS * OUTF);
  k_split3_t<<<(HID * HEADS * OUTF + 255) / 256, 256, 0, stream>>>(
      W3, W3Th, W3Tm, W3Tl, 11, 2047, OUTF, HID * HEADS * OUTF);

  // ---- layer-1 attention coefficients for ALL heads from x directly ----
  k_watt1<<<(IN_F * HEADS * 64 + 255) / 256, 256, 0, stream>>>(
      W1, attS1, attD1, watt);
  k_asad1<<<gW, 256, 0, stream>>>(x, watt, asall, adall, N);

  // ---- edge dtype detection + CSR-1 build (needed before step 0) ----
  k_detect<<<1, 256, 0, stream>>>(ei1, flag);

  k_init_deg<<<gN, 256, 0, stream>>>(wp1, N);
  k_count<<<gE, 256, 0, stream>>>(ei1, flag, wp1, E);
  k_scan<<<1, 1024, 0, stream>>>(wp1, rp1, N);
  k_fill_self<<<gN, 256, 0, stream>>>(rp1, wp1, col1, N);
  k_fill_edges<<<gE, 256, 0, stream>>>(ei1, flag, wp1, col1, E);

  if (pipe) {
    // ---- CSR-2 overlapped with layer-1 MFMA work ----
    float* buf[2] = {h1hA, h1hB};
    k_init_deg<<<gN, 256, 0, stream>>>(wp2, N);
    // prologue: gemm1(head0) || CSR-2 degree count
    prologue_k<<<GM1 * 2 + gE, 256, 0, stream>>>(
        x, W1Th, W1Tm, W1Tl, buf[0], N, ei2, flag, wp2, E, GM1 * 2);
    k_scan<<<1, 1024, 0, stream>>>(wp2, rp2, N);
    k_fill_self<<<gN, 256, 0, stream>>>(rp2, wp2, col2, N);

    // ---- software-pipelined layer 1: aggr(h) || gemm1(h+1) || gemm23(h-1)
    //      (step 0 also carries CSR-2 fill_edges as role E) ----
    for (int h = 0; h < HEADS; ++h) {
      int nG1 = (h + 1 < HEADS) ? GM1 * 2 : 0;
      int nG23 = (h >= 1) ? GM1 * 2 : 0;
      int nC = nG1 + nG23;
      int nE = (h == 0) ? gE : 0;
      int T = gW + nE + nC;
      if (9 * nC > T) T = 9 * nC;
      int hn = (h + 1 < HEADS) ? h + 1 : h;       // safe pointer when unused
      int hp = (h >= 1) ? h - 1 : 0;
      int sp = hp & 1;
      fused_step<<<T, 256, 0, stream>>>(
          rp1, col1, asall + (size_t)h * N, adall + (size_t)h * N,
          buf[h & 1], b1 + (size_t)h * HID,
          embH, embM, embL, (h & 1) * HID, ldE, N,
          x, W1Th + (size_t)hn * HID * IN_F, W1Tm + (size_t)hn * HID * IN_F,
          W1Tl + (size_t)hn * HID * IN_F, buf[(h + 1) & 1], nG1,
          embH + sp * HID, embM + sp * HID, embL + sp * HID,
          W2Th + (size_t)hp * HID, W2Tm + (size_t)hp * HID,
          W2Tl + (size_t)hp * HID,
          W3Th + (size_t)hp * HID, W3Tm + (size_t)hp * HID,
          h2, h3, hp > 0 ? 1 : 0, nG23,
          ei2, flag, wp2, col2, nE, E);
    }
    // final gemm23 for head 7 (emb slot 1)
    gemm23_k<<<dim3(GM1, 1, 2), 256, 0, stream>>>(
        embH + HID, embM + HID, embL + HID, ldE,
        W2Th + (size_t)7 * HID, W2Tm + (size_t)7 * HID, W2Tl + (size_t)7 * HID,
        W3Th + (size_t)7 * HID, W3Tm + (size_t)7 * HID, HID * HEADS,
        h2, h3, OUTF, N, HID, 1);
  } else {
    // ---- fallback: sequential per-head + serial CSR-2 ----
    k_init_deg<<<gN, 256, 0, stream>>>(wp2, N);
    k_count<<<gE, 256, 0, stream>>>(ei2, flag, wp2, E);
    k_scan<<<1, 1024, 0, stream>>>(wp2, rp2, N);
    k_fill_self<<<gN, 256, 0, stream>>>(rp2, wp2, col2, N);
    k_fill_edges<<<gE, 256, 0, stream>>>(ei2, flag, wp2, col2, E);
    for (int h = 0; h < HEADS; ++h) {
      gemm1_k<<<dim3(GM1, 2), 256, 0, stream>>>(
          x, IN_F,
          W1Th + (size_t)h * HID * IN_F, W1Tm + (size_t)h * HID * IN_F,
          W1Tl + (size_t)h * HID * IN_F, IN_F, h1hA, HID, N, IN_F);
      aggr_l1_fused<<<gW, 256, 0, stream>>>(
          rp1, col1, asall + (size_t)h * N, adall + (size_t)h * N, h1hA,
          b1 + (size_t)h * HID, embH, embM, embL, 0, ldE, N);
      gemm23_k<<<dim3(GM1, 1, 2), 256, 0, stream>>>(
          embH, embM, embL, ldE,
          W2Th + (size_t)h * HID, W2Tm + (size_t)h * HID,
          W2Tl + (size_t)h * HID,
          W3Th + (size_t)h * HID, W3Tm + (size_t)h * HID, HID * HEADS,
          h2, h3, OUTF, N, HID, h > 0 ? 1 : 0);
    }
  }

  // ---- layer 2 attention + aggregation (heads=1), dual dispatches ----
  att_dot_dual<<<2 * gW, 256, 0, stream>>>(
      h2, h3, attS2, attD2, attS3, attD3, as2, ad2, as3, ad3, N, gW);
  aggr_l2_dual<<<2 * gW, 256, 0, stream>>>(
      rp1, col1, as2, ad2, h2, b2, x1, pred,
      rp2, col2, as3, ad3, h3, b3, x2, N, gW);
}

// Round 10
// 3945.429 us; speedup vs baseline: 1.0125x; 1.0063x over previous
//
#include <hip/hip_runtime.h>
#include <hip/hip_bf16.h>
#include <math.h>

#define N_NODES 50000
#define E_EDGES 1600000
#define EP_EDGES (E_EDGES + N_NODES)
#define IN_F 512
#define HID 256
#define HEADS 8
#define OUTF 128

typedef unsigned short u16;
typedef __attribute__((ext_vector_type(8))) short short8;
typedef __attribute__((ext_vector_type(4))) float floatx4;

static __device__ __forceinline__ float eluf(float x) {
  return x > 0.f ? x : expm1f(x);
}

static __device__ __forceinline__ u16 bf16_hi(float v) {
  __hip_bfloat16 h = __float2bfloat16(v);
  return *(u16*)&h;
}
static __device__ __forceinline__ float bf16_f(u16 u) {
  __hip_bfloat16 h = *(__hip_bfloat16*)&u;
  return __bfloat162float(h);
}
// 3-way split: v ~= h + m + l, each bf16 (~24 mantissa bits total)
static __device__ __forceinline__ void split3_bf16(float v, u16& h, u16& m, u16& l) {
  h = bf16_hi(v);
  float r1 = v - bf16_f(h);
  m = bf16_hi(r1);
  float r2 = r1 - bf16_f(m);
  l = bf16_hi(r2);
}

// clamp index to [0, n)
static __device__ __forceinline__ int clampi(int v, int n) {
  return v < 0 ? 0 : (v >= n ? n - 1 : v);
}

// ---------------- CSR build ----------------

__global__ void k_detect(const int* __restrict__ ei, int* __restrict__ flag) {
  __shared__ int nz;
  if (threadIdx.x == 0) nz = 0;
  __syncthreads();
  for (int i = threadIdx.x; i < 4096; i += blockDim.x)
    if (ei[2 * i + 1] != 0) nz = 1;   // benign race
  __syncthreads();
  if (threadIdx.x == 0) *flag = (nz ? 0 : 1);
}

__global__ void k_init_deg(int* __restrict__ deg, int n) {
  int i = blockIdx.x * 256 + threadIdx.x;
  if (i < n) deg[i] = 1;   // self loop
}

__global__ void k_count(const int* __restrict__ ei, const int* __restrict__ flag,
                        int* __restrict__ deg, int E) {
  int e = blockIdx.x * 256 + threadIdx.x;
  if (e >= E) return;
  int f = *flag;
  int idx = E + e;                       // row 1 = dst
  int dst = clampi(ei[f ? 2 * idx : idx], N_NODES);
  atomicAdd(&deg[dst], 1);
}

// wave-shfl based scan: inclusive scan of deg -> rp[1..n], rp[0]=0.
__global__ __launch_bounds__(1024) void k_scan(const int* __restrict__ deg,
                                               int* __restrict__ rp, int n) {
  __shared__ int sw[16];
  __shared__ int s_run;
  int tid = threadIdx.x, lane = tid & 63, w = tid >> 6;
  if (tid == 0) s_run = 0;
  __syncthreads();
  for (int base = 0; base < n; base += 1024) {
    int i = base + tid;
    int v = (i < n) ? deg[i] : 0;
    int sv = v;
#pragma unroll
    for (int off = 1; off < 64; off <<= 1) {
      int t = __shfl_up(sv, off);
      if (lane >= off) sv += t;
    }
    if (lane == 63) sw[w] = sv;
    __syncthreads();
    if (w == 0) {
      int wsum = (lane < 16) ? sw[lane] : 0;
#pragma unroll
      for (int off = 1; off < 16; off <<= 1) {
        int t = __shfl_up(wsum, off);
        if (lane >= off) wsum += t;
      }
      if (lane < 16) sw[lane] = wsum;
    }
    __syncthreads();
    int woff = (w > 0) ? sw[w - 1] : 0;
    int run = s_run;
    if (i < n) rp[i + 1] = run + woff + sv;
    __syncthreads();
    if (tid == 1023) s_run = run + sw[15];
    __syncthreads();
  }
  if (tid == 0) rp[0] = 0;
}

__global__ void k_fill_self(const int* __restrict__ rp, int* __restrict__ wp,
                            int* __restrict__ col, int n) {
  int i = blockIdx.x * 256 + threadIdx.x;
  if (i < n) { int p = rp[i]; col[p] = i; wp[i] = p + 1; }
}

__global__ void k_fill_edges(const int* __restrict__ ei, const int* __restrict__ flag,
                             int* __restrict__ wp, int* __restrict__ col, int E) {
  int e = blockIdx.x * 256 + threadIdx.x;
  if (e >= E) return;
  int f = *flag;
  int src = clampi(ei[f ? 2 * e : e], N_NODES);
  int didx = E + e;
  int dst = clampi(ei[f ? 2 * didx : didx], N_NODES);
  int p = atomicAdd(&wp[dst], 1);
  col[p] = src;
}

// ---------------- weight transpose + 3-way split ----------------
__global__ void k_split3_t(const float* __restrict__ W, u16* __restrict__ H,
                           u16* __restrict__ Mv, u16* __restrict__ L,
                           int kshift, int kmask, int Nw, int total) {
  int idx = blockIdx.x * 256 + threadIdx.x;
  if (idx >= total) return;
  int n = idx >> kshift;
  int k = idx & kmask;
  u16 h, m, l;
  split3_bf16(W[(size_t)k * Nw + n], h, m, l);
  H[idx] = h;
  Mv[idx] = m;
  L[idx] = l;
}

// ---------------- attention projection: w_att = W1_h @ att ----------------
__global__ __launch_bounds__(256) void k_watt1(
    const float* __restrict__ W1, const float* __restrict__ attS,
    const float* __restrict__ attD, float* __restrict__ watt) {
  int wid = (blockIdx.x * 256 + threadIdx.x) >> 6;   // one wave per (k,h)
  int lane = threadIdx.x & 63;
  if (wid >= IN_F * HEADS) return;
  int k = wid >> 3, h = wid & 7;
  float4 wv = *(const float4*)&W1[(size_t)k * (HID * HEADS) + h * HID + lane * 4];
  float4 sv = *(const float4*)&attS[h * HID + lane * 4];
  float4 dv = *(const float4*)&attD[h * HID + lane * 4];
  float s = wv.x * sv.x + wv.y * sv.y + wv.z * sv.z + wv.w * sv.w;
  float d = wv.x * dv.x + wv.y * dv.y + wv.z * dv.z + wv.w * dv.w;
  for (int off = 32; off; off >>= 1) {
    s += __shfl_xor(s, off);
    d += __shfl_xor(d, off);
  }
  if (lane == 0) {
    watt[(size_t)(2 * h) * IN_F + k] = s;
    watt[(size_t)(2 * h + 1) * IN_F + k] = d;
  }
}

// a_src/a_dst for ALL heads in one pass over x.
__global__ __launch_bounds__(256) void k_asad1(
    const float* __restrict__ x, const float* __restrict__ watt,
    float* __restrict__ asall, float* __restrict__ adall, int n) {
  int node = (blockIdx.x * 256 + threadIdx.x) >> 6;
  int lane = threadIdx.x & 63;
  if (node >= n) return;
  float4 x0 = *(const float4*)&x[(size_t)node * IN_F + lane * 8];
  float4 x1 = *(const float4*)&x[(size_t)node * IN_F + lane * 8 + 4];
  for (int h = 0; h < HEADS; ++h) {
    const float* ws = watt + (size_t)(2 * h) * IN_F + lane * 8;
    const float* wd = watt + (size_t)(2 * h + 1) * IN_F + lane * 8;
    float4 s0 = *(const float4*)ws, s1 = *(const float4*)(ws + 4);
    float4 d0 = *(const float4*)wd, d1 = *(const float4*)(wd + 4);
    float s = x0.x * s0.x + x0.y * s0.y + x0.z * s0.z + x0.w * s0.w
            + x1.x * s1.x + x1.y * s1.y + x1.z * s1.z + x1.w * s1.w;
    float d = x0.x * d0.x + x0.y * d0.y + x0.z * d0.z + x0.w * d0.w
            + x1.x * d1.x + x1.y * d1.y + x1.z * d1.z + x1.w * d1.w;
    for (int off = 32; off; off >>= 1) {
      s += __shfl_xor(s, off);
      d += __shfl_xor(d, off);
    }
    if (lane == 0) {
      asall[(size_t)h * n + node] = s;
      adall[(size_t)h * n + node] = d;
    }
  }
}

// ---------------- split-bf16 MFMA GEMM machinery ----------------
#define GBM 128
#define GBN 128
#define GBK 32
#define GM1 391   // ceil(50000/128)

#define MFMA_BF16 __builtin_amdgcn_mfma_f32_16x16x32_bf16

__device__ __forceinline__ void gemm_epilogue(floatx4 acc[4][4], float* C,
                                              int ldc, int M, int accum,
                                              int row0, int col0, int wr,
                                              int wc, int lane) {
  int q = lane >> 4, n15 = lane & 15;
#pragma unroll
  for (int i = 0; i < 4; ++i) {
#pragma unroll
    for (int r = 0; r < 4; ++r) {
      int row = row0 + wr * 64 + i * 16 + q * 4 + r;
      if (row < M) {
#pragma unroll
        for (int j = 0; j < 4; ++j) {
          int cg = col0 + wc * 64 + j * 16 + n15;
          float v = acc[i][j][r];
          if (accum) v += C[(size_t)row * ldc + cg];
          C[(size_t)row * ldc + cg] = v;
        }
      }
    }
  }
}

// GEMM1 core: A = x (fp32, split 3-way on the fly), B pre-split 3-way.
__device__ __forceinline__ void gemm1_core(
    const float* __restrict__ X, int lda,
    const u16* __restrict__ Bh, const u16* __restrict__ Bm,
    const u16* __restrict__ Bl, int ldb,
    float* __restrict__ C, int ldc, int M, int K, int row0, int col0,
    u16* lds) {
  int tid = threadIdx.x;
  int lane = tid & 63, wave = tid >> 6;
  int wr = wave >> 1, wc = wave & 1;
  floatx4 acc[4][4] = {};
  int m0 = tid >> 2, m1 = (tid + 256) >> 2;
  int q0 = tid & 3;
  int lo0 = ((m0 >> 4) * 64 + q0 * 16 + (m0 & 15)) * 8;
  int lo1 = ((m1 >> 4) * 64 + q0 * 16 + (m1 & 15)) * 8;

  for (int k0 = 0; k0 < K; k0 += GBK) {
#pragma unroll
    for (int c = 0; c < 2; ++c) {
      int m = c ? m1 : m0;
      int lo = c ? lo1 : lo0;
      int gr = row0 + m;
      float f[8];
      if (gr < M) {
        float4 f0 = *(const float4*)(X + (size_t)gr * lda + k0 + q0 * 8);
        float4 f1 = *(const float4*)(X + (size_t)gr * lda + k0 + q0 * 8 + 4);
        f[0] = f0.x; f[1] = f0.y; f[2] = f0.z; f[3] = f0.w;
        f[4] = f1.x; f[5] = f1.y; f[6] = f1.z; f[7] = f1.w;
      } else {
#pragma unroll
        for (int e = 0; e < 8; ++e) f[e] = 0.f;
      }
      short8 vh, vm, vl;
#pragma unroll
      for (int e = 0; e < 8; ++e) {
        u16 h, m2, l;
        split3_bf16(f[e], h, m2, l);
        vh[e] = (short)h; vm[e] = (short)m2; vl[e] = (short)l;
      }
      *(short8*)&lds[lo] = vh;
      *(short8*)&lds[4096 + lo] = vm;
      *(short8*)&lds[8192 + lo] = vl;
    }
#pragma unroll
    for (int c = 0; c < 2; ++c) {
      int m = c ? m1 : m0;
      int lo = c ? lo1 : lo0;
      size_t go = (size_t)(col0 + m) * ldb + k0 + q0 * 8;
      *(short8*)&lds[12288 + lo] = *(const short8*)(Bh + go);
      *(short8*)&lds[16384 + lo] = *(const short8*)(Bm + go);
      *(short8*)&lds[20480 + lo] = *(const short8*)(Bl + go);
    }
    __syncthreads();
    short8 a_h[4], a_m[4], a_l[4];
#pragma unroll
    for (int i = 0; i < 4; ++i) {
      int o = ((wr * 4 + i) * 64 + lane) * 8;
      a_h[i] = *(short8*)&lds[o];
      a_m[i] = *(short8*)&lds[4096 + o];
      a_l[i] = *(short8*)&lds[8192 + o];
    }
#pragma unroll
    for (int j = 0; j < 4; ++j) {
      int o = ((wc * 4 + j) * 64 + lane) * 8;
      short8 b_h = *(short8*)&lds[12288 + o];
      short8 b_m = *(short8*)&lds[16384 + o];
      short8 b_l = *(short8*)&lds[20480 + o];
#pragma unroll
      for (int i = 0; i < 4; ++i) {
        acc[i][j] = MFMA_BF16(a_l[i], b_h, acc[i][j], 0, 0, 0);
        acc[i][j] = MFMA_BF16(a_m[i], b_m, acc[i][j], 0, 0, 0);
        acc[i][j] = MFMA_BF16(a_h[i], b_l, acc[i][j], 0, 0, 0);
        acc[i][j] = MFMA_BF16(a_m[i], b_h, acc[i][j], 0, 0, 0);
        acc[i][j] = MFMA_BF16(a_h[i], b_m, acc[i][j], 0, 0, 0);
        acc[i][j] = MFMA_BF16(a_h[i], b_h, acc[i][j], 0, 0, 0);
      }
    }
    __syncthreads();
  }
  gemm_epilogue(acc, C, ldc, M, 0, row0, col0, wr, wc, lane);
}

__global__ __launch_bounds__(256) void gemm1_k(
    const float* __restrict__ X, int lda,
    const u16* __restrict__ Bh, const u16* __restrict__ Bm,
    const u16* __restrict__ Bl, int ldb,
    float* __restrict__ C, int ldc, int M, int K) {
  __shared__ __align__(16) u16 lds[24576];
  gemm1_core(X, lda, Bh, Bm, Bl, ldb, C, ldc, M, K,
             blockIdx.x * GBM, blockIdx.y * GBN, lds);
}

// prologue: gemm1(head0) tiles || CSR-2 degree count (independent roles).
// Grid is EXACTLY nG + ceil(E2/256): no rounding overflow blocks.
__global__ __launch_bounds__(256) void prologue_k(
    const float* __restrict__ X,
    const u16* __restrict__ Bh, const u16* __restrict__ Bm,
    const u16* __restrict__ Bl, float* __restrict__ C, int M,
    const int* __restrict__ ei2, const int* __restrict__ flag,
    int* __restrict__ deg2, int E2, int nG) {
  __shared__ __align__(16) u16 lds[24576];
  int b = blockIdx.x;
  if (b < nG) {
    int bx = b % GM1, by = b / GM1;
    gemm1_core(X, IN_F, Bh, Bm, Bl, IN_F, C, HID, M, IN_F,
               bx * GBM, by * GBN, lds);
    return;
  }
  int e = (b - nG) * 256 + threadIdx.x;
  if (e >= E2) return;
  int f = *flag;
  int idx = E2 + e;                      // row 1 = dst
  int dst = clampi(ei2[f ? 2 * idx : idx], N_NODES);
  atomicAdd(&deg2[dst], 1);
}

// 6-term core with pre-split A (used for h2). accum flag.
__device__ __forceinline__ void gemm_core6(
    const u16* __restrict__ Ah, const u16* __restrict__ Am,
    const u16* __restrict__ Al, int lda,
    const u16* __restrict__ Bh, const u16* __restrict__ Bm,
    const u16* __restrict__ Bl, int ldb,
    float* __restrict__ C, int ldc, int M, int K, int row0, int col0,
    int accum, u16* lds) {
  int tid = threadIdx.x;
  int lane = tid & 63, wave = tid >> 6;
  int wr = wave >> 1, wc = wave & 1;
  floatx4 acc[4][4] = {};
  int m0 = tid >> 2, m1 = (tid + 256) >> 2;
  int q0 = tid & 3;
  int lo0 = ((m0 >> 4) * 64 + q0 * 16 + (m0 & 15)) * 8;
  int lo1 = ((m1 >> 4) * 64 + q0 * 16 + (m1 & 15)) * 8;
  for (int k0 = 0; k0 < K; k0 += GBK) {
#pragma unroll
    for (int c = 0; c < 2; ++c) {
      int m = c ? m1 : m0;
      int lo = c ? lo1 : lo0;
      int gr = row0 + m;
      short8 vh = {}, vm = {}, vl = {};
      if (gr < M) {
        size_t go = (size_t)gr * lda + k0 + q0 * 8;
        vh = *(const short8*)(Ah + go);
        vm = *(const short8*)(Am + go);
        vl = *(const short8*)(Al + go);
      }
      *(short8*)&lds[lo] = vh;
      *(short8*)&lds[4096 + lo] = vm;
      *(short8*)&lds[8192 + lo] = vl;
      size_t go = (size_t)(col0 + m) * ldb + k0 + q0 * 8;
      *(short8*)&lds[12288 + lo] = *(const short8*)(Bh + go);
      *(short8*)&lds[16384 + lo] = *(const short8*)(Bm + go);
      *(short8*)&lds[20480 + lo] = *(const short8*)(Bl + go);
    }
    __syncthreads();
    short8 a_h[4], a_m[4], a_l[4];
#pragma unroll
    for (int i = 0; i < 4; ++i) {
      int o = ((wr * 4 + i) * 64 + lane) * 8;
      a_h[i] = *(short8*)&lds[o];
      a_m[i] = *(short8*)&lds[4096 + o];
      a_l[i] = *(short8*)&lds[8192 + o];
    }
#pragma unroll
    for (int j = 0; j < 4; ++j) {
      int o = ((wc * 4 + j) * 64 + lane) * 8;
      short8 b_h = *(short8*)&lds[12288 + o];
      short8 b_m = *(short8*)&lds[16384 + o];
      short8 b_l = *(short8*)&lds[20480 + o];
#pragma unroll
      for (int i = 0; i < 4; ++i) {
        acc[i][j] = MFMA_BF16(a_l[i], b_h, acc[i][j], 0, 0, 0);
        acc[i][j] = MFMA_BF16(a_m[i], b_m, acc[i][j], 0, 0, 0);
        acc[i][j] = MFMA_BF16(a_h[i], b_l, acc[i][j], 0, 0, 0);
        acc[i][j] = MFMA_BF16(a_m[i], b_h, acc[i][j], 0, 0, 0);
        acc[i][j] = MFMA_BF16(a_h[i], b_m, acc[i][j], 0, 0, 0);
        acc[i][j] = MFMA_BF16(a_h[i], b_h, acc[i][j], 0, 0, 0);
      }
    }
    __syncthreads();
  }
  gemm_epilogue(acc, C, ldc, M, accum, row0, col0, wr, wc, lane);
}

// 3-term (2-way split) core — used for h3. accum flag.
__device__ __forceinline__ void gemm_core3(
    const u16* __restrict__ Ah, const u16* __restrict__ Am, int lda,
    const u16* __restrict__ Bh, const u16* __restrict__ Bm, int ldb,
    float* __restrict__ C, int ldc, int M, int K, int row0, int col0,
    int accum, u16* lds) {
  int tid = threadIdx.x;
  int lane = tid & 63, wave = tid >> 6;
  int wr = wave >> 1, wc = wave & 1;
  floatx4 acc[4][4] = {};
  int m0 = tid >> 2, m1 = (tid + 256) >> 2;
  int q0 = tid & 3;
  int lo0 = ((m0 >> 4) * 64 + q0 * 16 + (m0 & 15)) * 8;
  int lo1 = ((m1 >> 4) * 64 + q0 * 16 + (m1 & 15)) * 8;
  for (int k0 = 0; k0 < K; k0 += GBK) {
#pragma unroll
    for (int c = 0; c < 2; ++c) {
      int m = c ? m1 : m0;
      int lo = c ? lo1 : lo0;
      int gr = row0 + m;
      short8 vh = {}, vm = {};
      if (gr < M) {
        size_t go = (size_t)gr * lda + k0 + q0 * 8;
        vh = *(const short8*)(Ah + go);
        vm = *(const short8*)(Am + go);
      }
      *(short8*)&lds[lo] = vh;
      *(short8*)&lds[4096 + lo] = vm;
      size_t go = (size_t)(col0 + m) * ldb + k0 + q0 * 8;
      *(short8*)&lds[12288 + lo] = *(const short8*)(Bh + go);
      *(short8*)&lds[16384 + lo] = *(const short8*)(Bm + go);
    }
    __syncthreads();
    short8 a_h[4], a_m[4];
#pragma unroll
    for (int i = 0; i < 4; ++i) {
      int o = ((wr * 4 + i) * 64 + lane) * 8;
      a_h[i] = *(short8*)&lds[o];
      a_m[i] = *(short8*)&lds[4096 + o];
    }
#pragma unroll
    for (int j = 0; j < 4; ++j) {
      int o = ((wc * 4 + j) * 64 + lane) * 8;
      short8 b_h = *(short8*)&lds[12288 + o];
      short8 b_m = *(short8*)&lds[16384 + o];
#pragma unroll
      for (int i = 0; i < 4; ++i) {
        acc[i][j] = MFMA_BF16(a_m[i], b_h, acc[i][j], 0, 0, 0);
        acc[i][j] = MFMA_BF16(a_h[i], b_m, acc[i][j], 0, 0, 0);
        acc[i][j] = MFMA_BF16(a_h[i], b_h, acc[i][j], 0, 0, 0);
      }
    }
    __syncthreads();
  }
  gemm_epilogue(acc, C, ldc, M, accum, row0, col0, wr, wc, lane);
}

// standalone GEMM2/3 (used for the final head and the fallback path)
__global__ __launch_bounds__(256) void gemm23_k(
    const u16* __restrict__ Ah, const u16* __restrict__ Am,
    const u16* __restrict__ Al, int lda,
    const u16* __restrict__ B2h, const u16* __restrict__ B2m,
    const u16* __restrict__ B2l,
    const u16* __restrict__ B3h, const u16* __restrict__ B3m, int ldb,
    float* __restrict__ C2, float* __restrict__ C3, int ldc, int M, int K,
    int accum) {
  __shared__ __align__(16) u16 lds[24576];
  if (blockIdx.z == 0)
    gemm_core6(Ah, Am, Al, lda, B2h, B2m, B2l, ldb, C2, ldc, M, K,
               blockIdx.x * GBM, 0, accum, lds);
  else
    gemm_core3(Ah, Am, lda, B3h, B3m, ldb, C3, ldc, M, K,
               blockIdx.x * GBM, 0, accum, lds);
}

// ---------------- attention dot products (layer 2, both h2/h3) -----------
__global__ __launch_bounds__(256) void att_dot_dual(
    const float* __restrict__ h2, const float* __restrict__ h3,
    const float* __restrict__ s2, const float* __restrict__ d2,
    const float* __restrict__ s3, const float* __restrict__ d3,
    float* __restrict__ as2, float* __restrict__ ad2,
    float* __restrict__ as3, float* __restrict__ ad3, int n, int gW) {
  int b = blockIdx.x;
  int second = (b >= gW) ? 1 : 0;
  int bb = second ? b - gW : b;
  const float* h  = second ? h3 : h2;
  const float* sS = second ? s3 : s2;
  const float* sD = second ? d3 : d2;
  float* oS = second ? as3 : as2;
  float* oD = second ? ad3 : ad2;
  int node = (bb * 256 + threadIdx.x) >> 6;
  int lane = threadIdx.x & 63;
  if (node >= n) return;
  float2 hv = *(const float2*)&h[(size_t)node * OUTF + lane * 2];
  float2 sv = *(const float2*)&sS[lane * 2];
  float2 dv = *(const float2*)&sD[lane * 2];
  float s = hv.x * sv.x + hv.y * sv.y;
  float d = hv.x * dv.x + hv.y * dv.y;
  for (int off = 32; off; off >>= 1) {
    s += __shfl_xor(s, off);
    d += __shfl_xor(d, off);
  }
  if (lane == 0) { oS[node] = s; oD[node] = d; }
}

// ---------------- layer-1 fused softmax + gather-aggregate core -----------
// 8 rows in flight per wave (measured-best depth).
static __device__ __forceinline__ void aggr_l1_core(
    int node, int lane,
    const int* __restrict__ rp, const int* __restrict__ col,
    const float* __restrict__ aS, const float* __restrict__ aD,
    const float* __restrict__ h, const float* __restrict__ bias,
    u16* __restrict__ embH, u16* __restrict__ embM, u16* __restrict__ embL,
    int ecol0, int ldE, int n) {
  int s0 = rp[node], s1 = rp[node + 1];
  int d = s1 - s0;
  float ad = aD[node];
  float4 acc = make_float4(0.f, 0.f, 0.f, 0.f);

  if (d <= 64) {
    int c = 0;
    float e = -3.0e38f;
    if (lane < d) {
      c = clampi(col[s0 + lane], n);
      float t = aS[c] + ad;
      e = t >= 0.f ? t : 0.2f * t;
    }
    float m = e;
    for (int off = 32; off; off >>= 1) m = fmaxf(m, __shfl_xor(m, off));
    float ex = (lane < d) ? expf(e - m) : 0.f;
    float s = ex;
    for (int off = 32; off; off >>= 1) s += __shfl_xor(s, off);
    float al = ex * (1.f / (s + 1e-16f));   // 0 for lanes >= d
    int d8 = d & ~7;
    for (int j = 0; j < d8; j += 8) {
#pragma unroll
      for (int t = 0; t < 8; ++t) {
        int ct = __shfl(c, j + t);
        float at = __shfl(al, j + t);
        float4 hv = *(const float4*)&h[(size_t)ct * HID + lane * 4];
        acc.x += at * hv.x; acc.y += at * hv.y;
        acc.z += at * hv.z; acc.w += at * hv.w;
      }
    }
    if (d8 < d) {
#pragma unroll
      for (int t = 0; t < 8; ++t) {
        if (d8 + t < d) {    // wave-uniform branch (d is per-wave scalar)
          int ct = __shfl(c, d8 + t);
          float at = __shfl(al, d8 + t);
          float4 hv = *(const float4*)&h[(size_t)ct * HID + lane * 4];
          acc.x += at * hv.x; acc.y += at * hv.y;
          acc.z += at * hv.z; acc.w += at * hv.w;
        }
      }
    }
  } else {
    float m = -3.0e38f;
    for (int i = s0 + lane; i < s1; i += 64) {
      float e = aS[clampi(col[i], n)] + ad;
      e = e >= 0.f ? e : 0.2f * e;
      m = fmaxf(m, e);
    }
    for (int off = 32; off; off >>= 1) m = fmaxf(m, __shfl_xor(m, off));
    float sum = 0.f;
    for (int i = s0 + lane; i < s1; i += 64) {
      float e = aS[clampi(col[i], n)] + ad;
      e = e >= 0.f ? e : 0.2f * e;
      sum += expf(e - m);
    }
    for (int off = 32; off; off >>= 1) sum += __shfl_xor(sum, off);
    float inv = 1.f / (sum + 1e-16f);
    for (int i = s0; i < s1; ++i) {
      int ci = clampi(col[i], n);
      float e = aS[ci] + ad;
      e = e >= 0.f ? e : 0.2f * e;
      float a = expf(e - m) * inv;
      float4 hv = *(const float4*)&h[(size_t)ci * HID + lane * 4];
      acc.x += a * hv.x; acc.y += a * hv.y; acc.z += a * hv.z; acc.w += a * hv.w;
    }
  }

  float4 bb = *(const float4*)&bias[lane * 4];
  float v0 = eluf(acc.x + bb.x);
  float v1 = eluf(acc.y + bb.y);
  float v2 = eluf(acc.z + bb.z);
  float v3 = eluf(acc.w + bb.w);
  ushort4 uh, um, ul;
  split3_bf16(v0, uh.x, um.x, ul.x);
  split3_bf16(v1, uh.y, um.y, ul.y);
  split3_bf16(v2, uh.z, um.z, ul.z);
  split3_bf16(v3, uh.w, um.w, ul.w);
  size_t o = (size_t)node * ldE + ecol0 + lane * 4;
  *(ushort4*)&embH[o] = uh;
  *(ushort4*)&embM[o] = um;
  *(ushort4*)&embL[o] = ul;
}

__global__ __launch_bounds__(256) void aggr_l1_fused(
    const int* __restrict__ rp, const int* __restrict__ col,
    const float* __restrict__ aS, const float* __restrict__ aD,
    const float* __restrict__ h, const float* __restrict__ bias,
    u16* __restrict__ embH, u16* __restrict__ embM, u16* __restrict__ embL,
    int ecol0, int ldE, int n) {
  int node = (blockIdx.x * 256 + threadIdx.x) >> 6;
  int lane = threadIdx.x & 63;
  if (node >= n) return;
  aggr_l1_core(node, lane, rp, col, aS, aD, h, bias, embH, embM, embL,
               ecol0, ldE, n);
}

// ---------------- fused pipeline step (round-8 exact form) ----------------
// One dispatch runs three independent roles (block-level):
//   role A (bulk): aggr(h)       — fabric-bound random gather
//   role B:        gemm1(h+1)    — MFMA-bound          (nG1 blocks)
//   role C:        gemm23(h-1)   — MFMA-bound          (nG23 blocks)
// Compute blocks are striped at every 9th blockIdx so each CU holds an
// ~8:1 aggr:gemm mix throughout the dispatch (overlap, not phases).
__global__ __launch_bounds__(256) void fused_step(
    // role A
    const int* __restrict__ rp, const int* __restrict__ col,
    const float* __restrict__ aS, const float* __restrict__ aD,
    const float* __restrict__ hg, const float* __restrict__ bias,
    u16* __restrict__ embH, u16* __restrict__ embM, u16* __restrict__ embL,
    int ecol0, int ldE, int n,
    // role B
    const float* __restrict__ X,
    const u16* __restrict__ B1h, const u16* __restrict__ B1m,
    const u16* __restrict__ B1l, float* __restrict__ h1out, int nG1,
    // role C
    const u16* __restrict__ A23h, const u16* __restrict__ A23m,
    const u16* __restrict__ A23l,
    const u16* __restrict__ B2h, const u16* __restrict__ B2m,
    const u16* __restrict__ B2l,
    const u16* __restrict__ B3h, const u16* __restrict__ B3m,
    float* __restrict__ C2, float* __restrict__ C3, int accum, int nG23) {
  __shared__ __align__(16) u16 lds[24576];
  int nC = nG1 + nG23;
  int k = blockIdx.x;
  int q = k / 9, r = k - q * 9;
  if (r == 0 && q < nC) {
    if (q < nG1) {
      int bx = q % GM1, by = q / GM1;
      gemm1_core(X, IN_F, B1h, B1m, B1l, IN_F, h1out, HID, n, IN_F,
                 bx * GBM, by * GBN, lds);
    } else {
      int p = q - nG1;
      int z = p / GM1, bx = p - z * GM1;
      if (z == 0)
        gemm_core6(A23h, A23m, A23l, ldE, B2h, B2m, B2l, HID * HEADS,
                   C2, OUTF, n, HID, bx * GBM, 0, accum, lds);
      else
        gemm_core3(A23h, A23m, ldE, B3h, B3m, HID * HEADS,
                   C3, OUTF, n, HID, bx * GBM, 0, accum, lds);
    }
    return;
  }
  int skipped = q + (r ? 1 : 0);
  if (skipped > nC) skipped = nC;
  int aggrIdx = k - skipped;
  int node = aggrIdx * 4 + (threadIdx.x >> 6);
  int lane = threadIdx.x & 63;
  if (node >= n) return;
  aggr_l1_core(node, lane, rp, col, aS, aD, hg, bias, embH, embM, embL,
               ecol0, ldE, n);
}

// ---------------- layer-2 dual: softmax + gather + row-softmax ------------
// Blocks [0,gW) -> x1 (graph1/h2, with predictions); [gW,2gW) -> x2.
__global__ __launch_bounds__(256) void aggr_l2_dual(
    const int* __restrict__ rp1, const int* __restrict__ col1,
    const float* __restrict__ as2, const float* __restrict__ ad2,
    const float* __restrict__ h2, const float* __restrict__ b2,
    float* __restrict__ x1, float* __restrict__ pred,
    const int* __restrict__ rp2, const int* __restrict__ col2,
    const float* __restrict__ as3, const float* __restrict__ ad3,
    const float* __restrict__ h3, const float* __restrict__ b3,
    float* __restrict__ x2, int n, int gW) {
  int b = blockIdx.x;
  int second = (b >= gW) ? 1 : 0;
  int bb = second ? b - gW : b;
  const int* rp = second ? rp2 : rp1;
  const int* col = second ? col2 : col1;
  const float* aS = second ? as3 : as2;
  const float* aD = second ? ad3 : ad2;
  const float* h = second ? h3 : h2;
  const float* bias = second ? b3 : b2;
  float* out = second ? x2 : x1;
  float* pr = second ? nullptr : pred;

  int node = (bb * 256 + threadIdx.x) >> 6;
  int lane = threadIdx.x & 63;
  if (node >= n) return;
  int s0 = rp[node], s1 = rp[node + 1];
  int d = s1 - s0;
  float ad = aD[node];
  float2 acc = make_float2(0.f, 0.f);

  if (d <= 64) {
    int c = 0;
    float e = -3.0e38f;
    if (lane < d) {
      c = clampi(col[s0 + lane], n);
      float t = aS[c] + ad;
      e = t >= 0.f ? t : 0.2f * t;
    }
    float m = e;
    for (int off = 32; off; off >>= 1) m = fmaxf(m, __shfl_xor(m, off));
    float ex = (lane < d) ? expf(e - m) : 0.f;
    float s = ex;
    for (int off = 32; off; off >>= 1) s += __shfl_xor(s, off);
    float al = ex * (1.f / (s + 1e-16f));
    int d8 = d & ~7;
    for (int j = 0; j < d8; j += 8) {
#pragma unroll
      for (int t = 0; t < 8; ++t) {
        int ct = __shfl(c, j + t);
        float at = __shfl(al, j + t);
        float2 hv = *(const float2*)&h[(size_t)ct * OUTF + lane * 2];
        acc.x += at * hv.x; acc.y += at * hv.y;
      }
    }
    if (d8 < d) {
#pragma unroll
      for (int t = 0; t < 8; ++t) {
        if (d8 + t < d) {   // wave-uniform
          int ct = __shfl(c, d8 + t);
          float at = __shfl(al, d8 + t);
          float2 hv = *(const float2*)&h[(size_t)ct * OUTF + lane * 2];
          acc.x += at * hv.x; acc.y += at * hv.y;
        }
      }
    }
  } else {
    float m = -3.0e38f;
    for (int i = s0 + lane; i < s1; i += 64) {
      float e = aS[clampi(col[i], n)] + ad;
      e = e >= 0.f ? e : 0.2f * e;
      m = fmaxf(m, e);
    }
    for (int off = 32; off; off >>= 1) m = fmaxf(m, __shfl_xor(m, off));
    float sum = 0.f;
    for (int i = s0 + lane; i < s1; i += 64) {
      float e = aS[clampi(col[i], n)] + ad;
      e = e >= 0.f ? e : 0.2f * e;
      sum += expf(e - m);
    }
    for (int off = 32; off; off >>= 1) sum += __shfl_xor(sum, off);
    float inv = 1.f / (sum + 1e-16f);
    for (int i = s0; i < s1; ++i) {
      int ci = clampi(col[i], n);
      float e = aS[ci] + ad;
      e = e >= 0.f ? e : 0.2f * e;
      float a = expf(e - m) * inv;
      float2 hv = *(const float2*)&h[(size_t)ci * OUTF + lane * 2];
      acc.x += a * hv.x; acc.y += a * hv.y;
    }
  }

  float2 bb2 = *(const float2*)&bias[lane * 2];
  acc.x += bb2.x; acc.y += bb2.y;

  // ---- fused row softmax + argmax ----
  float bv;
  int bi;
  if (acc.y > acc.x) { bv = acc.y; bi = 2 * lane + 1; }
  else               { bv = acc.x; bi = 2 * lane; }
  for (int off = 32; off; off >>= 1) {
    float ov = __shfl_xor(bv, off);
    int oi = __shfl_xor(bi, off);
    if (ov > bv || (ov == bv && oi < bi)) { bv = ov; bi = oi; }
  }
  float e0 = expf(acc.x - bv), e1 = expf(acc.y - bv);
  float ssum = e0 + e1;
  for (int off = 32; off; off >>= 1) ssum += __shfl_xor(ssum, off);
  float2 r;
  r.x = e0 / ssum;
  r.y = e1 / ssum;
  *(float2*)&out[(size_t)node * OUTF + lane * 2] = r;
  if (pr != nullptr && lane == 0) pr[node] = (float)bi;
}

// ---------------- host orchestration ----------------
extern "C" void kernel_launch(void* const* d_in, const int* in_sizes, int n_in,
                              void* d_out, int out_size, void* d_ws, size_t ws_size,
                              hipStream_t stream) {
  const int N = N_NODES, E = E_EDGES;
  const float* x     = (const float*)d_in[0];
  const int*   ei1   = (const int*)d_in[1];
  const int*   ei2   = (const int*)d_in[2];
  const float* W1    = (const float*)d_in[3];
  const float* attS1 = (const float*)d_in[4];
  const float* attD1 = (const float*)d_in[5];
  const float* b1    = (const float*)d_in[6];
  const float* W2    = (const float*)d_in[7];
  const float* attS2 = (const float*)d_in[8];
  const float* attD2 = (const float*)d_in[9];
  const float* b2    = (const float*)d_in[10];
  const float* W3    = (const float*)d_in[11];
  const float* attS3 = (const float*)d_in[12];
  const float* attD3 = (const float*)d_in[13];
  const float* b3    = (const float*)d_in[14];

  // ---- decide pipelined vs fallback by workspace size ----
  size_t needPipe =
      2 * ((size_t)EP_EDGES * 4) + 2 * ((size_t)(N + 1) * 4) +
      2 * ((size_t)N * 4) + 4096 +
      2 * ((size_t)N * HID * 4) +                      // h1h x2
      3 * ((size_t)N * 512 * 2) +                      // emb (2-head wide)
      (size_t)N * OUTF * 4 * 2 +                       // h2+h3
      3 * ((size_t)IN_F * HID * HEADS * 2) +           // W1T
      6 * ((size_t)HID * HEADS * OUTF * 2) +           // W2T/W3T
      2 * ((size_t)HEADS * N * 4) +                    // asall/adall
      4 * ((size_t)N * 4) +                            // as2..ad3
      (size_t)2 * HEADS * IN_F * 4 +                   // watt
      (size_t)(8 << 20);                               // slack
  int pipe = (ws_size >= needPipe) ? 1 : 0;
  const int nbuf = pipe ? 2 : 1;
  const int ldE = pipe ? 512 : 256;

  char* ws = (char*)d_ws;
  size_t off = 0;
  auto take = [&](size_t bytes) {
    off = (off + 255) & ~(size_t)255;
    size_t o = off;
    off += bytes;
    return o;
  };
  int*   col1 = (int*)(ws + take((size_t)EP_EDGES * 4));
  int*   col2 = (int*)(ws + take((size_t)EP_EDGES * 4));
  int*   rp1  = (int*)(ws + take((size_t)(N + 1) * 4));
  int*   rp2  = (int*)(ws + take((size_t)(N + 1) * 4));
  int*   wp1  = (int*)(ws + take((size_t)N * 4));
  int*   wp2  = (int*)(ws + take((size_t)N * 4));
  int*   flag = (int*)(ws + take(256));
  float* h1hA = (float*)(ws + take((size_t)N * HID * 4 * nbuf));
  float* h1hB = pipe ? h1hA + (size_t)N * HID : h1hA;
  u16*   embH = (u16*)(ws + take((size_t)N * ldE * 2));
  u16*   embM = (u16*)(ws + take((size_t)N * ldE * 2));
  u16*   embL = (u16*)(ws + take((size_t)N * ldE * 2));
  float* h2   = (float*)(ws + take((size_t)N * OUTF * 4 * 2));  // h2+h3
  float* h3   = h2 + (size_t)N * OUTF;
  u16*   W1Th = (u16*)(ws + take((size_t)IN_F * HID * HEADS * 2));  // [2048][512]
  u16*   W1Tm = (u16*)(ws + take((size_t)IN_F * HID * HEADS * 2));
  u16*   W1Tl = (u16*)(ws + take((size_t)IN_F * HID * HEADS * 2));
  u16*   W2Th = (u16*)(ws + take((size_t)HID * HEADS * OUTF * 2)); // [128][2048]
  u16*   W2Tm = (u16*)(ws + take((size_t)HID * HEADS * OUTF * 2));
  u16*   W2Tl = (u16*)(ws + take((size_t)HID * HEADS * OUTF * 2));
  u16*   W3Th = (u16*)(ws + take((size_t)HID * HEADS * OUTF * 2));
  u16*   W3Tm = (u16*)(ws + take((size_t)HID * HEADS * OUTF * 2));
  u16*   W3Tl = (u16*)(ws + take((size_t)HID * HEADS * OUTF * 2)); // dummy L
  float* asall = (float*)(ws + take((size_t)HEADS * N * 4));
  float* adall = (float*)(ws + take((size_t)HEADS * N * 4));
  float* as2  = (float*)(ws + take((size_t)N * 4));
  float* ad2  = (float*)(ws + take((size_t)N * 4));
  float* as3  = (float*)(ws + take((size_t)N * 4));
  float* ad3  = (float*)(ws + take((size_t)N * 4));
  float* watt = (float*)(ws + take((size_t)2 * HEADS * IN_F * 4));

  float* outp = (float*)d_out;
  float* x1   = outp;                         // logits   [N,128]
  float* x2   = outp + (size_t)N * OUTF;      // logits_2 [N,128]
  float* pred = outp + (size_t)2 * N * OUTF;  // predictions [N]

  const int gN = (N + 255) / 256;
  const int gE = (E + 255) / 256;               // 6250
  const int gW = (N + 3) / 4;                   // one wave per node = 12500

  // ---- weight transpose + 3-way splits ----
  k_split3_t<<<(IN_F * HID * HEADS + 255) / 256, 256, 0, stream>>>(
      W1, W1Th, W1Tm, W1Tl, 9, 511, HID * HEADS, IN_F * HID * HEADS);
  k_split3_t<<<(HID * HEADS * OUTF + 255) / 256, 256, 0, stream>>>(
      W2, W2Th, W2Tm, W2Tl, 11, 2047, OUTF, HID * HEADS * OUTF);
  k_split3_t<<<(HID * HEADS * OUTF + 255) / 256, 256, 0, stream>>>(
      W3, W3Th, W3Tm, W3Tl, 11, 2047, OUTF, HID * HEADS * OUTF);

  // ---- layer-1 attention coefficients for ALL heads from x directly ----
  k_watt1<<<(IN_F * HEADS * 64 + 255) / 256, 256, 0, stream>>>(
      W1, attS1, attD1, watt);
  k_asad1<<<gW, 256, 0, stream>>>(x, watt, asall, adall, N);

  // ---- edge dtype detection + CSR-1 build (needed before step 0) ----
  k_detect<<<1, 256, 0, stream>>>(ei1, flag);

  k_init_deg<<<gN, 256, 0, stream>>>(wp1, N);
  k_count<<<gE, 256, 0, stream>>>(ei1, flag, wp1, E);
  k_scan<<<1, 1024, 0, stream>>>(wp1, rp1, N);
  k_fill_self<<<gN, 256, 0, stream>>>(rp1, wp1, col1, N);
  k_fill_edges<<<gE, 256, 0, stream>>>(ei1, flag, wp1, col1, E);

  if (pipe) {
    // ---- CSR-2 count overlapped with gemm1(head0); fill standalone ----
    float* buf[2] = {h1hA, h1hB};
    k_init_deg<<<gN, 256, 0, stream>>>(wp2, N);
    prologue_k<<<GM1 * 2 + gE, 256, 0, stream>>>(
        x, W1Th, W1Tm, W1Tl, buf[0], N, ei2, flag, wp2, E, GM1 * 2);
    k_scan<<<1, 1024, 0, stream>>>(wp2, rp2, N);
    k_fill_self<<<gN, 256, 0, stream>>>(rp2, wp2, col2, N);
    k_fill_edges<<<gE, 256, 0, stream>>>(ei2, flag, wp2, col2, E);

    // ---- software-pipelined layer 1: aggr(h) || gemm1(h+1) || gemm23(h-1)
    for (int h = 0; h < HEADS; ++h) {
      int nG1 = (h + 1 < HEADS) ? GM1 * 2 : 0;
      int nG23 = (h >= 1) ? GM1 * 2 : 0;
      int nC = nG1 + nG23;
      int T = gW + nC;
      if (9 * nC > T) T = 9 * nC;
      int hn = (h + 1 < HEADS) ? h + 1 : h;       // safe pointer when unused
      int hp = (h >= 1) ? h - 1 : 0;
      int sp = hp & 1;
      fused_step<<<T, 256, 0, stream>>>(
          rp1, col1, asall + (size_t)h * N, adall + (size_t)h * N,
          buf[h & 1], b1 + (size_t)h * HID,
          embH, embM, embL, (h & 1) * HID, ldE, N,
          x, W1Th + (size_t)hn * HID * IN_F, W1Tm + (size_t)hn * HID * IN_F,
          W1Tl + (size_t)hn * HID * IN_F, buf[(h + 1) & 1], nG1,
          embH + sp * HID, embM + sp * HID, embL + sp * HID,
          W2Th + (size_t)hp * HID, W2Tm + (size_t)hp * HID,
          W2Tl + (size_t)hp * HID,
          W3Th + (size_t)hp * HID, W3Tm + (size_t)hp * HID,
          h2, h3, hp > 0 ? 1 : 0, nG23);
    }
    // final gemm23 for head 7 (emb slot 1)
    gemm23_k<<<dim3(GM1, 1, 2), 256, 0, stream>>>(
        embH + HID, embM + HID, embL + HID, ldE,
        W2Th + (size_t)7 * HID, W2Tm + (size_t)7 * HID, W2Tl + (size_t)7 * HID,
        W3Th + (size_t)7 * HID, W3Tm + (size_t)7 * HID, HID * HEADS,
        h2, h3, OUTF, N, HID, 1);
  } else {
    // ---- fallback: sequential per-head + serial CSR-2 ----
    k_init_deg<<<gN, 256, 0, stream>>>(wp2, N);
    k_count<<<gE, 256, 0, stream>>>(ei2, flag, wp2, E);
    k_scan<<<1, 1024, 0, stream>>>(wp2, rp2, N);
    k_fill_self<<<gN, 256, 0, stream>>>(rp2, wp2, col2, N);
    k_fill_edges<<<gE, 256, 0, stream>>>(ei2, flag, wp2, col2, E);
    for (int h = 0; h < HEADS; ++h) {
      gemm1_k<<<dim3(GM1, 2), 256, 0, stream>>>(
          x, IN_F,
          W1Th + (size_t)h * HID * IN_F, W1Tm + (size_t)h * HID * IN_F,
          W1Tl + (size_t)h * HID * IN_F, IN_F, h1hA, HID, N, IN_F);
      aggr_l1_fused<<<gW, 256, 0, stream>>>(
          rp1, col1, asall + (size_t)h * N, adall + (size_t)h * N, h1hA,
          b1 + (size_t)h * HID, embH, embM, embL, 0, ldE, N);
      gemm23_k<<<dim3(GM1, 1, 2), 256, 0, stream>>>(
          embH, embM, embL, ldE,
          W2Th + (size_t)h * HID, W2Tm + (size_t)h * HID,
          W2Tl + (size_t)h * HID,
          W3Th + (size_t)h * HID, W3Tm + (size_t)h * HID, HID * HEADS,
          h2, h3, OUTF, N, HID, h > 0 ? 1 : 0);
    }
  }

  // ---- layer 2 attention + aggregation (heads=1), dual dispatches ----
  att_dot_dual<<<2 * gW, 256, 0, stream>>>(
      h2, h3, attS2, attD2, attS3, attD3, as2, ad2, as3, ad3, N, gW);
  aggr_l2_dual<<<2 * gW, 256, 0, stream>>>(
      rp1, col1, as2, ad2, h2, b2, x1, pred,
      rp2, col2, as3, ad3, h3, b3, x2, N, gW);
}

// Round 11
// 3873.330 us; speedup vs baseline: 1.0313x; 1.0186x over previous
//
#include <hip/hip_runtime.h>
#include <hip/hip_bf16.h>
#include <math.h>

#define N_NODES 50000
#define E_EDGES 1600000
#define EP_EDGES (E_EDGES + N_NODES)
#define IN_F 512
#define HID 256
#define HEADS 8
#define OUTF 128

typedef unsigned short u16;
typedef __attribute__((ext_vector_type(8))) short short8;
typedef __attribute__((ext_vector_type(4))) float floatx4;

static __device__ __forceinline__ float eluf(float x) {
  return x > 0.f ? x : expm1f(x);
}

static __device__ __forceinline__ u16 bf16_hi(float v) {
  __hip_bfloat16 h = __float2bfloat16(v);
  return *(u16*)&h;
}
static __device__ __forceinline__ float bf16_f(u16 u) {
  __hip_bfloat16 h = *(__hip_bfloat16*)&u;
  return __bfloat162float(h);
}
// 3-way split: v ~= h + m + l, each bf16 (~24 mantissa bits total)
static __device__ __forceinline__ void split3_bf16(float v, u16& h, u16& m, u16& l) {
  h = bf16_hi(v);
  float r1 = v - bf16_f(h);
  m = bf16_hi(r1);
  float r2 = r1 - bf16_f(m);
  l = bf16_hi(r2);
}

// clamp index to [0, n)
static __device__ __forceinline__ int clampi(int v, int n) {
  return v < 0 ? 0 : (v >= n ? n - 1 : v);
}

// ---------------- CSR build ----------------

__global__ void k_detect(const int* __restrict__ ei, int* __restrict__ flag) {
  __shared__ int nz;
  if (threadIdx.x == 0) nz = 0;
  __syncthreads();
  for (int i = threadIdx.x; i < 4096; i += blockDim.x)
    if (ei[2 * i + 1] != 0) nz = 1;   // benign race
  __syncthreads();
  if (threadIdx.x == 0) *flag = (nz ? 0 : 1);
}

__global__ void k_init_deg(int* __restrict__ deg, int n) {
  int i = blockIdx.x * 256 + threadIdx.x;
  if (i < n) deg[i] = 1;   // self loop
}

__global__ void k_count(const int* __restrict__ ei, const int* __restrict__ flag,
                        int* __restrict__ deg, int E) {
  int e = blockIdx.x * 256 + threadIdx.x;
  if (e >= E) return;
  int f = *flag;
  int idx = E + e;                       // row 1 = dst
  int dst = clampi(ei[f ? 2 * idx : idx], N_NODES);
  atomicAdd(&deg[dst], 1);
}

// wave-shfl based scan body: inclusive scan of deg -> rp[1..n], rp[0]=0.
static __device__ __forceinline__ void scan_body(const int* __restrict__ deg,
                                                 int* __restrict__ rp, int n) {
  __shared__ int sw[16];
  __shared__ int s_run;
  int tid = threadIdx.x, lane = tid & 63, w = tid >> 6;
  if (tid == 0) s_run = 0;
  __syncthreads();
  for (int base = 0; base < n; base += 1024) {
    int i = base + tid;
    int v = (i < n) ? deg[i] : 0;
    int sv = v;
#pragma unroll
    for (int off = 1; off < 64; off <<= 1) {
      int t = __shfl_up(sv, off);
      if (lane >= off) sv += t;
    }
    if (lane == 63) sw[w] = sv;
    __syncthreads();
    if (w == 0) {
      int wsum = (lane < 16) ? sw[lane] : 0;
#pragma unroll
      for (int off = 1; off < 16; off <<= 1) {
        int t = __shfl_up(wsum, off);
        if (lane >= off) wsum += t;
      }
      if (lane < 16) sw[lane] = wsum;
    }
    __syncthreads();
    int woff = (w > 0) ? sw[w - 1] : 0;
    int run = s_run;
    if (i < n) rp[i + 1] = run + woff + sv;
    __syncthreads();
    if (tid == 1023) s_run = run + sw[15];
    __syncthreads();
  }
  if (tid == 0) rp[0] = 0;
}

__global__ __launch_bounds__(1024) void k_scan(const int* __restrict__ deg,
                                               int* __restrict__ rp, int n) {
  scan_body(deg, rp, n);
}

// both graphs in one dispatch (block 0 -> graph1, block 1 -> graph2)
__global__ __launch_bounds__(1024) void k_scan_dual(
    const int* __restrict__ degA, int* __restrict__ rpA,
    const int* __restrict__ degB, int* __restrict__ rpB, int n) {
  if (blockIdx.x == 0) scan_body(degA, rpA, n);
  else                 scan_body(degB, rpB, n);
}

__global__ void k_fill_self(const int* __restrict__ rp, int* __restrict__ wp,
                            int* __restrict__ col, int n) {
  int i = blockIdx.x * 256 + threadIdx.x;
  if (i < n) { int p = rp[i]; col[p] = i; wp[i] = p + 1; }
}

__global__ void k_fill_self_dual(
    const int* __restrict__ rpA, int* __restrict__ wpA, int* __restrict__ colA,
    const int* __restrict__ rpB, int* __restrict__ wpB, int* __restrict__ colB,
    int n, int gN) {
  int b = blockIdx.x;
  const int* rp; int* wp; int* col;
  if (b < gN) { rp = rpA; wp = wpA; col = colA; }
  else        { rp = rpB; wp = wpB; col = colB; b -= gN; }
  int i = b * 256 + threadIdx.x;
  if (i < n) { int p = rp[i]; col[p] = i; wp[i] = p + 1; }
}

__global__ void k_fill_edges(const int* __restrict__ ei, const int* __restrict__ flag,
                             int* __restrict__ wp, int* __restrict__ col, int E) {
  int e = blockIdx.x * 256 + threadIdx.x;
  if (e >= E) return;
  int f = *flag;
  int src = clampi(ei[f ? 2 * e : e], N_NODES);
  int didx = E + e;
  int dst = clampi(ei[f ? 2 * didx : didx], N_NODES);
  int p = atomicAdd(&wp[dst], 1);
  col[p] = src;
}

__global__ void k_fill_edges_dual(
    const int* __restrict__ eiA, const int* __restrict__ eiB,
    const int* __restrict__ flag,
    int* __restrict__ wpA, int* __restrict__ colA,
    int* __restrict__ wpB, int* __restrict__ colB, int E, int gE) {
  int b = blockIdx.x;
  const int* ei; int* wp; int* col;
  if (b < gE) { ei = eiA; wp = wpA; col = colA; }
  else        { ei = eiB; wp = wpB; col = colB; b -= gE; }
  int e = b * 256 + threadIdx.x;
  if (e >= E) return;
  int f = *flag;
  int src = clampi(ei[f ? 2 * e : e], N_NODES);
  int didx = E + e;
  int dst = clampi(ei[f ? 2 * didx : didx], N_NODES);
  int p = atomicAdd(&wp[dst], 1);
  col[p] = src;
}

// ---------------- weight transpose + 3-way split ----------------
__global__ void k_split3_t(const float* __restrict__ W, u16* __restrict__ H,
                           u16* __restrict__ Mv, u16* __restrict__ L,
                           int kshift, int kmask, int Nw, int total) {
  int idx = blockIdx.x * 256 + threadIdx.x;
  if (idx >= total) return;
  int n = idx >> kshift;
  int k = idx & kmask;
  u16 h, m, l;
  split3_bf16(W[(size_t)k * Nw + n], h, m, l);
  H[idx] = h;
  Mv[idx] = m;
  L[idx] = l;
}

// ---------------- attention projection: w_att = W1_h @ att ----------------
__global__ __launch_bounds__(256) void k_watt1(
    const float* __restrict__ W1, const float* __restrict__ attS,
    const float* __restrict__ attD, float* __restrict__ watt) {
  int wid = (blockIdx.x * 256 + threadIdx.x) >> 6;   // one wave per (k,h)
  int lane = threadIdx.x & 63;
  if (wid >= IN_F * HEADS) return;
  int k = wid >> 3, h = wid & 7;
  float4 wv = *(const float4*)&W1[(size_t)k * (HID * HEADS) + h * HID + lane * 4];
  float4 sv = *(const float4*)&attS[h * HID + lane * 4];
  float4 dv = *(const float4*)&attD[h * HID + lane * 4];
  float s = wv.x * sv.x + wv.y * sv.y + wv.z * sv.z + wv.w * sv.w;
  float d = wv.x * dv.x + wv.y * dv.y + wv.z * dv.z + wv.w * dv.w;
  for (int off = 32; off; off >>= 1) {
    s += __shfl_xor(s, off);
    d += __shfl_xor(d, off);
  }
  if (lane == 0) {
    watt[(size_t)(2 * h) * IN_F + k] = s;
    watt[(size_t)(2 * h + 1) * IN_F + k] = d;
  }
}

// a_src/a_dst body for ALL heads in one pass over x (one wave per node).
static __device__ __forceinline__ void asad_body(
    int node, int lane, const float* __restrict__ x,
    const float* __restrict__ watt,
    float* __restrict__ asall, float* __restrict__ adall, int n) {
  float4 x0 = *(const float4*)&x[(size_t)node * IN_F + lane * 8];
  float4 x1 = *(const float4*)&x[(size_t)node * IN_F + lane * 8 + 4];
  for (int h = 0; h < HEADS; ++h) {
    const float* ws = watt + (size_t)(2 * h) * IN_F + lane * 8;
    const float* wd = watt + (size_t)(2 * h + 1) * IN_F + lane * 8;
    float4 s0 = *(const float4*)ws, s1 = *(const float4*)(ws + 4);
    float4 d0 = *(const float4*)wd, d1 = *(const float4*)(wd + 4);
    float s = x0.x * s0.x + x0.y * s0.y + x0.z * s0.z + x0.w * s0.w
            + x1.x * s1.x + x1.y * s1.y + x1.z * s1.z + x1.w * s1.w;
    float d = x0.x * d0.x + x0.y * d0.y + x0.z * d0.z + x0.w * d0.w
            + x1.x * d1.x + x1.y * d1.y + x1.z * d1.z + x1.w * d1.w;
    for (int off = 32; off; off >>= 1) {
      s += __shfl_xor(s, off);
      d += __shfl_xor(d, off);
    }
    if (lane == 0) {
      asall[(size_t)h * n + node] = s;
      adall[(size_t)h * n + node] = d;
    }
  }
}

__global__ __launch_bounds__(256) void k_asad1(
    const float* __restrict__ x, const float* __restrict__ watt,
    float* __restrict__ asall, float* __restrict__ adall, int n) {
  int node = (blockIdx.x * 256 + threadIdx.x) >> 6;
  int lane = threadIdx.x & 63;
  if (node >= n) return;
  asad_body(node, lane, x, watt, asall, adall, n);
}

// ---------------- split-bf16 MFMA GEMM machinery ----------------
#define GBM 128
#define GBN 128
#define GBK 32
#define GM1 391   // ceil(50000/128)

#define MFMA_BF16 __builtin_amdgcn_mfma_f32_16x16x32_bf16

__device__ __forceinline__ void gemm_epilogue(floatx4 acc[4][4], float* C,
                                              int ldc, int M, int accum,
                                              int row0, int col0, int wr,
                                              int wc, int lane) {
  int q = lane >> 4, n15 = lane & 15;
#pragma unroll
  for (int i = 0; i < 4; ++i) {
#pragma unroll
    for (int r = 0; r < 4; ++r) {
      int row = row0 + wr * 64 + i * 16 + q * 4 + r;
      if (row < M) {
#pragma unroll
        for (int j = 0; j < 4; ++j) {
          int cg = col0 + wc * 64 + j * 16 + n15;
          float v = acc[i][j][r];
          if (accum) v += C[(size_t)row * ldc + cg];
          C[(size_t)row * ldc + cg] = v;
        }
      }
    }
  }
}

// GEMM1 core: A = x (fp32, split 3-way on the fly), B pre-split 3-way.
__device__ __forceinline__ void gemm1_core(
    const float* __restrict__ X, int lda,
    const u16* __restrict__ Bh, const u16* __restrict__ Bm,
    const u16* __restrict__ Bl, int ldb,
    float* __restrict__ C, int ldc, int M, int K, int row0, int col0,
    u16* lds) {
  int tid = threadIdx.x;
  int lane = tid & 63, wave = tid >> 6;
  int wr = wave >> 1, wc = wave & 1;
  floatx4 acc[4][4] = {};
  int m0 = tid >> 2, m1 = (tid + 256) >> 2;
  int q0 = tid & 3;
  int lo0 = ((m0 >> 4) * 64 + q0 * 16 + (m0 & 15)) * 8;
  int lo1 = ((m1 >> 4) * 64 + q0 * 16 + (m1 & 15)) * 8;

  for (int k0 = 0; k0 < K; k0 += GBK) {
#pragma unroll
    for (int c = 0; c < 2; ++c) {
      int m = c ? m1 : m0;
      int lo = c ? lo1 : lo0;
      int gr = row0 + m;
      float f[8];
      if (gr < M) {
        float4 f0 = *(const float4*)(X + (size_t)gr * lda + k0 + q0 * 8);
        float4 f1 = *(const float4*)(X + (size_t)gr * lda + k0 + q0 * 8 + 4);
        f[0] = f0.x; f[1] = f0.y; f[2] = f0.z; f[3] = f0.w;
        f[4] = f1.x; f[5] = f1.y; f[6] = f1.z; f[7] = f1.w;
      } else {
#pragma unroll
        for (int e = 0; e < 8; ++e) f[e] = 0.f;
      }
      short8 vh, vm, vl;
#pragma unroll
      for (int e = 0; e < 8; ++e) {
        u16 h, m2, l;
        split3_bf16(f[e], h, m2, l);
        vh[e] = (short)h; vm[e] = (short)m2; vl[e] = (short)l;
      }
      *(short8*)&lds[lo] = vh;
      *(short8*)&lds[4096 + lo] = vm;
      *(short8*)&lds[8192 + lo] = vl;
    }
#pragma unroll
    for (int c = 0; c < 2; ++c) {
      int m = c ? m1 : m0;
      int lo = c ? lo1 : lo0;
      size_t go = (size_t)(col0 + m) * ldb + k0 + q0 * 8;
      *(short8*)&lds[12288 + lo] = *(const short8*)(Bh + go);
      *(short8*)&lds[16384 + lo] = *(const short8*)(Bm + go);
      *(short8*)&lds[20480 + lo] = *(const short8*)(Bl + go);
    }
    __syncthreads();
    short8 a_h[4], a_m[4], a_l[4];
#pragma unroll
    for (int i = 0; i < 4; ++i) {
      int o = ((wr * 4 + i) * 64 + lane) * 8;
      a_h[i] = *(short8*)&lds[o];
      a_m[i] = *(short8*)&lds[4096 + o];
      a_l[i] = *(short8*)&lds[8192 + o];
    }
#pragma unroll
    for (int j = 0; j < 4; ++j) {
      int o = ((wc * 4 + j) * 64 + lane) * 8;
      short8 b_h = *(short8*)&lds[12288 + o];
      short8 b_m = *(short8*)&lds[16384 + o];
      short8 b_l = *(short8*)&lds[20480 + o];
#pragma unroll
      for (int i = 0; i < 4; ++i) {
        acc[i][j] = MFMA_BF16(a_l[i], b_h, acc[i][j], 0, 0, 0);
        acc[i][j] = MFMA_BF16(a_m[i], b_m, acc[i][j], 0, 0, 0);
        acc[i][j] = MFMA_BF16(a_h[i], b_l, acc[i][j], 0, 0, 0);
        acc[i][j] = MFMA_BF16(a_m[i], b_h, acc[i][j], 0, 0, 0);
        acc[i][j] = MFMA_BF16(a_h[i], b_m, acc[i][j], 0, 0, 0);
        acc[i][j] = MFMA_BF16(a_h[i], b_h, acc[i][j], 0, 0, 0);
      }
    }
    __syncthreads();
  }
  gemm_epilogue(acc, C, ldc, M, 0, row0, col0, wr, wc, lane);
}

__global__ __launch_bounds__(256) void gemm1_k(
    const float* __restrict__ X, int lda,
    const u16* __restrict__ Bh, const u16* __restrict__ Bm,
    const u16* __restrict__ Bl, int ldb,
    float* __restrict__ C, int ldc, int M, int K) {
  __shared__ __align__(16) u16 lds[24576];
  gemm1_core(X, lda, Bh, Bm, Bl, ldb, C, ldc, M, K,
             blockIdx.x * GBM, blockIdx.y * GBN, lds);
}

// prologue: gemm1(head0) || CSR-1 count || CSR-2 count || asad1.
// Grid is EXACTLY nG + 2*nCE + ceil(n*4/256): no rounding overflow blocks.
__global__ __launch_bounds__(256) void prologue_k(
    const float* __restrict__ X,
    const u16* __restrict__ Bh, const u16* __restrict__ Bm,
    const u16* __restrict__ Bl, float* __restrict__ C, int M,
    const int* __restrict__ ei1, const int* __restrict__ ei2,
    const int* __restrict__ flag,
    int* __restrict__ deg1, int* __restrict__ deg2, int E2,
    const float* __restrict__ watt,
    float* __restrict__ asall, float* __restrict__ adall,
    int nG, int nCE) {
  __shared__ __align__(16) u16 lds[24576];
  int b = blockIdx.x;
  if (b < nG) {
    int bx = b % GM1, by = b / GM1;
    gemm1_core(X, IN_F, Bh, Bm, Bl, IN_F, C, HID, M, IN_F,
               bx * GBM, by * GBN, lds);
    return;
  }
  b -= nG;
  if (b < 2 * nCE) {
    // count roles: first nCE blocks -> graph1, next nCE -> graph2
    const int* ei = (b < nCE) ? ei1 : ei2;
    int* deg = (b < nCE) ? deg1 : deg2;
    int bb = (b < nCE) ? b : b - nCE;
    int e = bb * 256 + (int)threadIdx.x;
    if (e >= E2) return;
    int f = *flag;
    int idx = E2 + e;                    // row 1 = dst
    int dst = clampi(ei[f ? 2 * idx : idx], N_NODES);
    atomicAdd(&deg[dst], 1);
    return;
  }
  b -= 2 * nCE;
  // asad role: one wave per node
  int node = (b * 256 + (int)threadIdx.x) >> 6;
  int lane = threadIdx.x & 63;
  if (node >= M) return;
  asad_body(node, lane, X, watt, asall, adall, M);
}

// 6-term core with pre-split A (used for h2). accum flag.
__device__ __forceinline__ void gemm_core6(
    const u16* __restrict__ Ah, const u16* __restrict__ Am,
    const u16* __restrict__ Al, int lda,
    const u16* __restrict__ Bh, const u16* __restrict__ Bm,
    const u16* __restrict__ Bl, int ldb,
    float* __restrict__ C, int ldc, int M, int K, int row0, int col0,
    int accum, u16* lds) {
  int tid = threadIdx.x;
  int lane = tid & 63, wave = tid >> 6;
  int wr = wave >> 1, wc = wave & 1;
  floatx4 acc[4][4] = {};
  int m0 = tid >> 2, m1 = (tid + 256) >> 2;
  int q0 = tid & 3;
  int lo0 = ((m0 >> 4) * 64 + q0 * 16 + (m0 & 15)) * 8;
  int lo1 = ((m1 >> 4) * 64 + q0 * 16 + (m1 & 15)) * 8;
  for (int k0 = 0; k0 < K; k0 += GBK) {
#pragma unroll
    for (int c = 0; c < 2; ++c) {
      int m = c ? m1 : m0;
      int lo = c ? lo1 : lo0;
      int gr = row0 + m;
      short8 vh = {}, vm = {}, vl = {};
      if (gr < M) {
        size_t go = (size_t)gr * lda + k0 + q0 * 8;
        vh = *(const short8*)(Ah + go);
        vm = *(const short8*)(Am + go);
        vl = *(const short8*)(Al + go);
      }
      *(short8*)&lds[lo] = vh;
      *(short8*)&lds[4096 + lo] = vm;
      *(short8*)&lds[8192 + lo] = vl;
      size_t go = (size_t)(col0 + m) * ldb + k0 + q0 * 8;
      *(short8*)&lds[12288 + lo] = *(const short8*)(Bh + go);
      *(short8*)&lds[16384 + lo] = *(const short8*)(Bm + go);
      *(short8*)&lds[20480 + lo] = *(const short8*)(Bl + go);
    }
    __syncthreads();
    short8 a_h[4], a_m[4], a_l[4];
#pragma unroll
    for (int i = 0; i < 4; ++i) {
      int o = ((wr * 4 + i) * 64 + lane) * 8;
      a_h[i] = *(short8*)&lds[o];
      a_m[i] = *(short8*)&lds[4096 + o];
      a_l[i] = *(short8*)&lds[8192 + o];
    }
#pragma unroll
    for (int j = 0; j < 4; ++j) {
      int o = ((wc * 4 + j) * 64 + lane) * 8;
      short8 b_h = *(short8*)&lds[12288 + o];
      short8 b_m = *(short8*)&lds[16384 + o];
      short8 b_l = *(short8*)&lds[20480 + o];
#pragma unroll
      for (int i = 0; i < 4; ++i) {
        acc[i][j] = MFMA_BF16(a_l[i], b_h, acc[i][j], 0, 0, 0);
        acc[i][j] = MFMA_BF16(a_m[i], b_m, acc[i][j], 0, 0, 0);
        acc[i][j] = MFMA_BF16(a_h[i], b_l, acc[i][j], 0, 0, 0);
        acc[i][j] = MFMA_BF16(a_m[i], b_h, acc[i][j], 0, 0, 0);
        acc[i][j] = MFMA_BF16(a_h[i], b_m, acc[i][j], 0, 0, 0);
        acc[i][j] = MFMA_BF16(a_h[i], b_h, acc[i][j], 0, 0, 0);
      }
    }
    __syncthreads();
  }
  gemm_epilogue(acc, C, ldc, M, accum, row0, col0, wr, wc, lane);
}

// 3-term (2-way split) core — used for h3. accum flag.
__device__ __forceinline__ void gemm_core3(
    const u16* __restrict__ Ah, const u16* __restrict__ Am, int lda,
    const u16* __restrict__ Bh, const u16* __restrict__ Bm, int ldb,
    float* __restrict__ C, int ldc, int M, int K, int row0, int col0,
    int accum, u16* lds) {
  int tid = threadIdx.x;
  int lane = tid & 63, wave = tid >> 6;
  int wr = wave >> 1, wc = wave & 1;
  floatx4 acc[4][4] = {};
  int m0 = tid >> 2, m1 = (tid + 256) >> 2;
  int q0 = tid & 3;
  int lo0 = ((m0 >> 4) * 64 + q0 * 16 + (m0 & 15)) * 8;
  int lo1 = ((m1 >> 4) * 64 + q0 * 16 + (m1 & 15)) * 8;
  for (int k0 = 0; k0 < K; k0 += GBK) {
#pragma unroll
    for (int c = 0; c < 2; ++c) {
      int m = c ? m1 : m0;
      int lo = c ? lo1 : lo0;
      int gr = row0 + m;
      short8 vh = {}, vm = {};
      if (gr < M) {
        size_t go = (size_t)gr * lda + k0 + q0 * 8;
        vh = *(const short8*)(Ah + go);
        vm = *(const short8*)(Am + go);
      }
      *(short8*)&lds[lo] = vh;
      *(short8*)&lds[4096 + lo] = vm;
      size_t go = (size_t)(col0 + m) * ldb + k0 + q0 * 8;
      *(short8*)&lds[12288 + lo] = *(const short8*)(Bh + go);
      *(short8*)&lds[16384 + lo] = *(const short8*)(Bm + go);
    }
    __syncthreads();
    short8 a_h[4], a_m[4];
#pragma unroll
    for (int i = 0; i < 4; ++i) {
      int o = ((wr * 4 + i) * 64 + lane) * 8;
      a_h[i] = *(short8*)&lds[o];
      a_m[i] = *(short8*)&lds[4096 + o];
    }
#pragma unroll
    for (int j = 0; j < 4; ++j) {
      int o = ((wc * 4 + j) * 64 + lane) * 8;
      short8 b_h = *(short8*)&lds[12288 + o];
      short8 b_m = *(short8*)&lds[16384 + o];
#pragma unroll
      for (int i = 0; i < 4; ++i) {
        acc[i][j] = MFMA_BF16(a_m[i], b_h, acc[i][j], 0, 0, 0);
        acc[i][j] = MFMA_BF16(a_h[i], b_m, acc[i][j], 0, 0, 0);
        acc[i][j] = MFMA_BF16(a_h[i], b_h, acc[i][j], 0, 0, 0);
      }
    }
    __syncthreads();
  }
  gemm_epilogue(acc, C, ldc, M, accum, row0, col0, wr, wc, lane);
}

// standalone GEMM2/3 (used for the final head and the fallback path)
__global__ __launch_bounds__(256) void gemm23_k(
    const u16* __restrict__ Ah, const u16* __restrict__ Am,
    const u16* __restrict__ Al, int lda,
    const u16* __restrict__ B2h, const u16* __restrict__ B2m,
    const u16* __restrict__ B2l,
    const u16* __restrict__ B3h, const u16* __restrict__ B3m, int ldb,
    float* __restrict__ C2, float* __restrict__ C3, int ldc, int M, int K,
    int accum) {
  __shared__ __align__(16) u16 lds[24576];
  if (blockIdx.z == 0)
    gemm_core6(Ah, Am, Al, lda, B2h, B2m, B2l, ldb, C2, ldc, M, K,
               blockIdx.x * GBM, 0, accum, lds);
  else
    gemm_core3(Ah, Am, lda, B3h, B3m, ldb, C3, ldc, M, K,
               blockIdx.x * GBM, 0, accum, lds);
}

// ---------------- attention dot products (layer 2, both h2/h3) -----------
__global__ __launch_bounds__(256) void att_dot_dual(
    const float* __restrict__ h2, const float* __restrict__ h3,
    const float* __restrict__ s2, const float* __restrict__ d2,
    const float* __restrict__ s3, const float* __restrict__ d3,
    float* __restrict__ as2, float* __restrict__ ad2,
    float* __restrict__ as3, float* __restrict__ ad3, int n, int gW) {
  int b = blockIdx.x;
  int second = (b >= gW) ? 1 : 0;
  int bb = second ? b - gW : b;
  const float* h  = second ? h3 : h2;
  const float* sS = second ? s3 : s2;
  const float* sD = second ? d3 : d2;
  float* oS = second ? as3 : as2;
  float* oD = second ? ad3 : ad2;
  int node = (bb * 256 + threadIdx.x) >> 6;
  int lane = threadIdx.x & 63;
  if (node >= n) return;
  float2 hv = *(const float2*)&h[(size_t)node * OUTF + lane * 2];
  float2 sv = *(const float2*)&sS[lane * 2];
  float2 dv = *(const float2*)&sD[lane * 2];
  float s = hv.x * sv.x + hv.y * sv.y;
  float d = hv.x * dv.x + hv.y * dv.y;
  for (int off = 32; off; off >>= 1) {
    s += __shfl_xor(s, off);
    d += __shfl_xor(d, off);
  }
  if (lane == 0) { oS[node] = s; oD[node] = d; }
}

// ---------------- layer-1 fused softmax + gather-aggregate core -----------
// 8 rows in flight per wave (measured-best depth).
static __device__ __forceinline__ void aggr_l1_core(
    int node, int lane,
    const int* __restrict__ rp, const int* __restrict__ col,
    const float* __restrict__ aS, const float* __restrict__ aD,
    const float* __restrict__ h, const float* __restrict__ bias,
    u16* __restrict__ embH, u16* __restrict__ embM, u16* __restrict__ embL,
    int ecol0, int ldE, int n) {
  int s0 = rp[node], s1 = rp[node + 1];
  int d = s1 - s0;
  float ad = aD[node];
  float4 acc = make_float4(0.f, 0.f, 0.f, 0.f);

  if (d <= 64) {
    int c = 0;
    float e = -3.0e38f;
    if (lane < d) {
      c = clampi(col[s0 + lane], n);
      float t = aS[c] + ad;
      e = t >= 0.f ? t : 0.2f * t;
    }
    float m = e;
    for (int off = 32; off; off >>= 1) m = fmaxf(m, __shfl_xor(m, off));
    float ex = (lane < d) ? expf(e - m) : 0.f;
    float s = ex;
    for (int off = 32; off; off >>= 1) s += __shfl_xor(s, off);
    float al = ex * (1.f / (s + 1e-16f));   // 0 for lanes >= d
    int d8 = d & ~7;
    for (int j = 0; j < d8; j += 8) {
#pragma unroll
      for (int t = 0; t < 8; ++t) {
        int ct = __shfl(c, j + t);
        float at = __shfl(al, j + t);
        float4 hv = *(const float4*)&h[(size_t)ct * HID + lane * 4];
        acc.x += at * hv.x; acc.y += at * hv.y;
        acc.z += at * hv.z; acc.w += at * hv.w;
      }
    }
    if (d8 < d) {
#pragma unroll
      for (int t = 0; t < 8; ++t) {
        if (d8 + t < d) {    // wave-uniform branch (d is per-wave scalar)
          int ct = __shfl(c, d8 + t);
          float at = __shfl(al, d8 + t);
          float4 hv = *(const float4*)&h[(size_t)ct * HID + lane * 4];
          acc.x += at * hv.x; acc.y += at * hv.y;
          acc.z += at * hv.z; acc.w += at * hv.w;
        }
      }
    }
  } else {
    float m = -3.0e38f;
    for (int i = s0 + lane; i < s1; i += 64) {
      float e = aS[clampi(col[i], n)] + ad;
      e = e >= 0.f ? e : 0.2f * e;
      m = fmaxf(m, e);
    }
    for (int off = 32; off; off >>= 1) m = fmaxf(m, __shfl_xor(m, off));
    float sum = 0.f;
    for (int i = s0 + lane; i < s1; i += 64) {
      float e = aS[clampi(col[i], n)] + ad;
      e = e >= 0.f ? e : 0.2f * e;
      sum += expf(e - m);
    }
    for (int off = 32; off; off >>= 1) sum += __shfl_xor(sum, off);
    float inv = 1.f / (sum + 1e-16f);
    for (int i = s0; i < s1; ++i) {
      int ci = clampi(col[i], n);
      float e = aS[ci] + ad;
      e = e >= 0.f ? e : 0.2f * e;
      float a = expf(e - m) * inv;
      float4 hv = *(const float4*)&h[(size_t)ci * HID + lane * 4];
      acc.x += a * hv.x; acc.y += a * hv.y; acc.z += a * hv.z; acc.w += a * hv.w;
    }
  }

  float4 bb = *(const float4*)&bias[lane * 4];
  float v0 = eluf(acc.x + bb.x);
  float v1 = eluf(acc.y + bb.y);
  float v2 = eluf(acc.z + bb.z);
  float v3 = eluf(acc.w + bb.w);
  ushort4 uh, um, ul;
  split3_bf16(v0, uh.x, um.x, ul.x);
  split3_bf16(v1, uh.y, um.y, ul.y);
  split3_bf16(v2, uh.z, um.z, ul.z);
  split3_bf16(v3, uh.w, um.w, ul.w);
  size_t o = (size_t)node * ldE + ecol0 + lane * 4;
  *(ushort4*)&embH[o] = uh;
  *(ushort4*)&embM[o] = um;
  *(ushort4*)&embL[o] = ul;
}

__global__ __launch_bounds__(256) void aggr_l1_fused(
    const int* __restrict__ rp, const int* __restrict__ col,
    const float* __restrict__ aS, const float* __restrict__ aD,
    const float* __restrict__ h, const float* __restrict__ bias,
    u16* __restrict__ embH, u16* __restrict__ embM, u16* __restrict__ embL,
    int ecol0, int ldE, int n) {
  int node = (blockIdx.x * 256 + threadIdx.x) >> 6;
  int lane = threadIdx.x & 63;
  if (node >= n) return;
  aggr_l1_core(node, lane, rp, col, aS, aD, h, bias, embH, embM, embL,
               ecol0, ldE, n);
}

// ---------------- fused pipeline step (FROZEN: round-8 exact form) --------
// One dispatch runs three independent roles (block-level):
//   role A (bulk): aggr(h)       — fabric-bound random gather
//   role B:        gemm1(h+1)    — MFMA-bound          (nG1 blocks)
//   role C:        gemm23(h-1)   — MFMA-bound          (nG23 blocks)
// Compute blocks are striped at every 9th blockIdx so each CU holds an
// ~8:1 aggr:gemm mix throughout the dispatch (overlap, not phases).
// DO NOT modify this kernel's signature or body: measured twice that any
// change (extra role/args) regresses steps 403 -> 440 us via codegen.
__global__ __launch_bounds__(256) void fused_step(
    // role A
    const int* __restrict__ rp, const int* __restrict__ col,
    const float* __restrict__ aS, const float* __restrict__ aD,
    const float* __restrict__ hg, const float* __restrict__ bias,
    u16* __restrict__ embH, u16* __restrict__ embM, u16* __restrict__ embL,
    int ecol0, int ldE, int n,
    // role B
    const float* __restrict__ X,
    const u16* __restrict__ B1h, const u16* __restrict__ B1m,
    const u16* __restrict__ B1l, float* __restrict__ h1out, int nG1,
    // role C
    const u16* __restrict__ A23h, const u16* __restrict__ A23m,
    const u16* __restrict__ A23l,
    const u16* __restrict__ B2h, const u16* __restrict__ B2m,
    const u16* __restrict__ B2l,
    const u16* __restrict__ B3h, const u16* __restrict__ B3m,
    float* __restrict__ C2, float* __restrict__ C3, int accum, int nG23) {
  __shared__ __align__(16) u16 lds[24576];
  int nC = nG1 + nG23;
  int k = blockIdx.x;
  int q = k / 9, r = k - q * 9;
  if (r == 0 && q < nC) {
    if (q < nG1) {
      int bx = q % GM1, by = q / GM1;
      gemm1_core(X, IN_F, B1h, B1m, B1l, IN_F, h1out, HID, n, IN_F,
                 bx * GBM, by * GBN, lds);
    } else {
      int p = q - nG1;
      int z = p / GM1, bx = p - z * GM1;
      if (z == 0)
        gemm_core6(A23h, A23m, A23l, ldE, B2h, B2m, B2l, HID * HEADS,
                   C2, OUTF, n, HID, bx * GBM, 0, accum, lds);
      else
        gemm_core3(A23h, A23m, ldE, B3h, B3m, HID * HEADS,
                   C3, OUTF, n, HID, bx * GBM, 0, accum, lds);
    }
    return;
  }
  int skipped = q + (r ? 1 : 0);
  if (skipped > nC) skipped = nC;
  int aggrIdx = k - skipped;
  int node = aggrIdx * 4 + (threadIdx.x >> 6);
  int lane = threadIdx.x & 63;
  if (node >= n) return;
  aggr_l1_core(node, lane, rp, col, aS, aD, hg, bias, embH, embM, embL,
               ecol0, ldE, n);
}

// ---------------- layer-2 dual: softmax + gather + row-softmax ------------
// Blocks [0,gW) -> x1 (graph1/h2, with predictions); [gW,2gW) -> x2.
__global__ __launch_bounds__(256) void aggr_l2_dual(
    const int* __restrict__ rp1, const int* __restrict__ col1,
    const float* __restrict__ as2, const float* __restrict__ ad2,
    const float* __restrict__ h2, const float* __restrict__ b2,
    float* __restrict__ x1, float* __restrict__ pred,
    const int* __restrict__ rp2, const int* __restrict__ col2,
    const float* __restrict__ as3, const float* __restrict__ ad3,
    const float* __restrict__ h3, const float* __restrict__ b3,
    float* __restrict__ x2, int n, int gW) {
  int b = blockIdx.x;
  int second = (b >= gW) ? 1 : 0;
  int bb = second ? b - gW : b;
  const int* rp = second ? rp2 : rp1;
  const int* col = second ? col2 : col1;
  const float* aS = second ? as3 : as2;
  const float* aD = second ? ad3 : ad2;
  const float* h = second ? h3 : h2;
  const float* bias = second ? b3 : b2;
  float* out = second ? x2 : x1;
  float* pr = second ? nullptr : pred;

  int node = (bb * 256 + threadIdx.x) >> 6;
  int lane = threadIdx.x & 63;
  if (node >= n) return;
  int s0 = rp[node], s1 = rp[node + 1];
  int d = s1 - s0;
  float ad = aD[node];
  float2 acc = make_float2(0.f, 0.f);

  if (d <= 64) {
    int c = 0;
    float e = -3.0e38f;
    if (lane < d) {
      c = clampi(col[s0 + lane], n);
      float t = aS[c] + ad;
      e = t >= 0.f ? t : 0.2f * t;
    }
    float m = e;
    for (int off = 32; off; off >>= 1) m = fmaxf(m, __shfl_xor(m, off));
    float ex = (lane < d) ? expf(e - m) : 0.f;
    float s = ex;
    for (int off = 32; off; off >>= 1) s += __shfl_xor(s, off);
    float al = ex * (1.f / (s + 1e-16f));
    int d8 = d & ~7;
    for (int j = 0; j < d8; j += 8) {
#pragma unroll
      for (int t = 0; t < 8; ++t) {
        int ct = __shfl(c, j + t);
        float at = __shfl(al, j + t);
        float2 hv = *(const float2*)&h[(size_t)ct * OUTF + lane * 2];
        acc.x += at * hv.x; acc.y += at * hv.y;
      }
    }
    if (d8 < d) {
#pragma unroll
      for (int t = 0; t < 8; ++t) {
        if (d8 + t < d) {   // wave-uniform
          int ct = __shfl(c, d8 + t);
          float at = __shfl(al, d8 + t);
          float2 hv = *(const float2*)&h[(size_t)ct * OUTF + lane * 2];
          acc.x += at * hv.x; acc.y += at * hv.y;
        }
      }
    }
  } else {
    float m = -3.0e38f;
    for (int i = s0 + lane; i < s1; i += 64) {
      float e = aS[clampi(col[i], n)] + ad;
      e = e >= 0.f ? e : 0.2f * e;
      m = fmaxf(m, e);
    }
    for (int off = 32; off; off >>= 1) m = fmaxf(m, __shfl_xor(m, off));
    float sum = 0.f;
    for (int i = s0 + lane; i < s1; i += 64) {
      float e = aS[clampi(col[i], n)] + ad;
      e = e >= 0.f ? e : 0.2f * e;
      sum += expf(e - m);
    }
    for (int off = 32; off; off >>= 1) sum += __shfl_xor(sum, off);
    float inv = 1.f / (sum + 1e-16f);
    for (int i = s0; i < s1; ++i) {
      int ci = clampi(col[i], n);
      float e = aS[ci] + ad;
      e = e >= 0.f ? e : 0.2f * e;
      float a = expf(e - m) * inv;
      float2 hv = *(const float2*)&h[(size_t)ci * OUTF + lane * 2];
      acc.x += a * hv.x; acc.y += a * hv.y;
    }
  }

  float2 bb2 = *(const float2*)&bias[lane * 2];
  acc.x += bb2.x; acc.y += bb2.y;

  // ---- fused row softmax + argmax ----
  float bv;
  int bi;
  if (acc.y > acc.x) { bv = acc.y; bi = 2 * lane + 1; }
  else               { bv = acc.x; bi = 2 * lane; }
  for (int off = 32; off; off >>= 1) {
    float ov = __shfl_xor(bv, off);
    int oi = __shfl_xor(bi, off);
    if (ov > bv || (ov == bv && oi < bi)) { bv = ov; bi = oi; }
  }
  float e0 = expf(acc.x - bv), e1 = expf(acc.y - bv);
  float ssum = e0 + e1;
  for (int off = 32; off; off >>= 1) ssum += __shfl_xor(ssum, off);
  float2 r;
  r.x = e0 / ssum;
  r.y = e1 / ssum;
  *(float2*)&out[(size_t)node * OUTF + lane * 2] = r;
  if (pr != nullptr && lane == 0) pr[node] = (float)bi;
}

// ---------------- host orchestration ----------------
extern "C" void kernel_launch(void* const* d_in, const int* in_sizes, int n_in,
                              void* d_out, int out_size, void* d_ws, size_t ws_size,
                              hipStream_t stream) {
  const int N = N_NODES, E = E_EDGES;
  const float* x     = (const float*)d_in[0];
  const int*   ei1   = (const int*)d_in[1];
  const int*   ei2   = (const int*)d_in[2];
  const float* W1    = (const float*)d_in[3];
  const float* attS1 = (const float*)d_in[4];
  const float* attD1 = (const float*)d_in[5];
  const float* b1    = (const float*)d_in[6];
  const float* W2    = (const float*)d_in[7];
  const float* attS2 = (const float*)d_in[8];
  const float* attD2 = (const float*)d_in[9];
  const float* b2    = (const float*)d_in[10];
  const float* W3    = (const float*)d_in[11];
  const float* attS3 = (const float*)d_in[12];
  const float* attD3 = (const float*)d_in[13];
  const float* b3    = (const float*)d_in[14];

  // ---- decide pipelined vs fallback by workspace size ----
  size_t needPipe =
      2 * ((size_t)EP_EDGES * 4) + 2 * ((size_t)(N + 1) * 4) +
      2 * ((size_t)N * 4) + 4096 +
      2 * ((size_t)N * HID * 4) +                      // h1h x2
      3 * ((size_t)N * 512 * 2) +                      // emb (2-head wide)
      (size_t)N * OUTF * 4 * 2 +                       // h2+h3
      3 * ((size_t)IN_F * HID * HEADS * 2) +           // W1T
      6 * ((size_t)HID * HEADS * OUTF * 2) +           // W2T/W3T
      2 * ((size_t)HEADS * N * 4) +                    // asall/adall
      4 * ((size_t)N * 4) +                            // as2..ad3
      (size_t)2 * HEADS * IN_F * 4 +                   // watt
      (size_t)(8 << 20);                               // slack
  int pipe = (ws_size >= needPipe) ? 1 : 0;
  const int nbuf = pipe ? 2 : 1;
  const int ldE = pipe ? 512 : 256;

  char* ws = (char*)d_ws;
  size_t off = 0;
  auto take = [&](size_t bytes) {
    off = (off + 255) & ~(size_t)255;
    size_t o = off;
    off += bytes;
    return o;
  };
  int*   col1 = (int*)(ws + take((size_t)EP_EDGES * 4));
  int*   col2 = (int*)(ws + take((size_t)EP_EDGES * 4));
  int*   rp1  = (int*)(ws + take((size_t)(N + 1) * 4));
  int*   rp2  = (int*)(ws + take((size_t)(N + 1) * 4));
  int*   wp1  = (int*)(ws + take((size_t)N * 4));
  int*   wp2  = (int*)(ws + take((size_t)N * 4));
  int*   flag = (int*)(ws + take(256));
  float* h1hA = (float*)(ws + take((size_t)N * HID * 4 * nbuf));
  float* h1hB = pipe ? h1hA + (size_t)N * HID : h1hA;
  u16*   embH = (u16*)(ws + take((size_t)N * ldE * 2));
  u16*   embM = (u16*)(ws + take((size_t)N * ldE * 2));
  u16*   embL = (u16*)(ws + take((size_t)N * ldE * 2));
  float* h2   = (float*)(ws + take((size_t)N * OUTF * 4 * 2));  // h2+h3
  float* h3   = h2 + (size_t)N * OUTF;
  u16*   W1Th = (u16*)(ws + take((size_t)IN_F * HID * HEADS * 2));  // [2048][512]
  u16*   W1Tm = (u16*)(ws + take((size_t)IN_F * HID * HEADS * 2));
  u16*   W1Tl = (u16*)(ws + take((size_t)IN_F * HID * HEADS * 2));
  u16*   W2Th = (u16*)(ws + take((size_t)HID * HEADS * OUTF * 2)); // [128][2048]
  u16*   W2Tm = (u16*)(ws + take((size_t)HID * HEADS * OUTF * 2));
  u16*   W2Tl = (u16*)(ws + take((size_t)HID * HEADS * OUTF * 2));
  u16*   W3Th = (u16*)(ws + take((size_t)HID * HEADS * OUTF * 2));
  u16*   W3Tm = (u16*)(ws + take((size_t)HID * HEADS * OUTF * 2));
  u16*   W3Tl = (u16*)(ws + take((size_t)HID * HEADS * OUTF * 2)); // dummy L
  float* asall = (float*)(ws + take((size_t)HEADS * N * 4));
  float* adall = (float*)(ws + take((size_t)HEADS * N * 4));
  float* as2  = (float*)(ws + take((size_t)N * 4));
  float* ad2  = (float*)(ws + take((size_t)N * 4));
  float* as3  = (float*)(ws + take((size_t)N * 4));
  float* ad3  = (float*)(ws + take((size_t)N * 4));
  float* watt = (float*)(ws + take((size_t)2 * HEADS * IN_F * 4));

  float* outp = (float*)d_out;
  float* x1   = outp;                         // logits   [N,128]
  float* x2   = outp + (size_t)N * OUTF;      // logits_2 [N,128]
  float* pred = outp + (size_t)2 * N * OUTF;  // predictions [N]

  const int gN = (N + 255) / 256;
  const int gE = (E + 255) / 256;               // 6250
  const int gW = (N + 3) / 4;                   // one wave per node = 12500

  // ---- weight transpose + 3-way splits ----
  k_split3_t<<<(IN_F * HID * HEADS + 255) / 256, 256, 0, stream>>>(
      W1, W1Th, W1Tm, W1Tl, 9, 511, HID * HEADS, IN_F * HID * HEADS);
  k_split3_t<<<(HID * HEADS * OUTF + 255) / 256, 256, 0, stream>>>(
      W2, W2Th, W2Tm, W2Tl, 11, 2047, OUTF, HID * HEADS * OUTF);
  k_split3_t<<<(HID * HEADS * OUTF + 255) / 256, 256, 0, stream>>>(
      W3, W3Th, W3Tm, W3Tl, 11, 2047, OUTF, HID * HEADS * OUTF);

  // ---- layer-1 attention projection + edge dtype detection ----
  k_watt1<<<(IN_F * HEADS * 64 + 255) / 256, 256, 0, stream>>>(
      W1, attS1, attD1, watt);
  k_detect<<<1, 256, 0, stream>>>(ei1, flag);

  if (pipe) {
    // ---- big prologue: gemm1(h0) || count1 || count2 || asad1 ----
    float* buf[2] = {h1hA, h1hB};
    k_init_deg<<<gN, 256, 0, stream>>>(wp1, N);
    k_init_deg<<<gN, 256, 0, stream>>>(wp2, N);
    prologue_k<<<GM1 * 2 + 2 * gE + gW, 256, 0, stream>>>(
        x, W1Th, W1Tm, W1Tl, buf[0], N,
        ei1, ei2, flag, wp1, wp2, E,
        watt, asall, adall, GM1 * 2, gE);
    // ---- CSR finish (both graphs in dual kernels) ----
    k_scan_dual<<<2, 1024, 0, stream>>>(wp1, rp1, wp2, rp2, N);
    k_fill_self_dual<<<2 * gN, 256, 0, stream>>>(
        rp1, wp1, col1, rp2, wp2, col2, N, gN);
    k_fill_edges_dual<<<2 * gE, 256, 0, stream>>>(
        ei1, ei2, flag, wp1, col1, wp2, col2, E, gE);

    // ---- software-pipelined layer 1: aggr(h) || gemm1(h+1) || gemm23(h-1)
    for (int h = 0; h < HEADS; ++h) {
      int nG1 = (h + 1 < HEADS) ? GM1 * 2 : 0;
      int nG23 = (h >= 1) ? GM1 * 2 : 0;
      int nC = nG1 + nG23;
      int T = gW + nC;
      if (9 * nC > T) T = 9 * nC;
      int hn = (h + 1 < HEADS) ? h + 1 : h;       // safe pointer when unused
      int hp = (h >= 1) ? h - 1 : 0;
      int sp = hp & 1;
      fused_step<<<T, 256, 0, stream>>>(
          rp1, col1, asall + (size_t)h * N, adall + (size_t)h * N,
          buf[h & 1], b1 + (size_t)h * HID,
          embH, embM, embL, (h & 1) * HID, ldE, N,
          x, W1Th + (size_t)hn * HID * IN_F, W1Tm + (size_t)hn * HID * IN_F,
          W1Tl + (size_t)hn * HID * IN_F, buf[(h + 1) & 1], nG1,
          embH + sp * HID, embM + sp * HID, embL + sp * HID,
          W2Th + (size_t)hp * HID, W2Tm + (size_t)hp * HID,
          W2Tl + (size_t)hp * HID,
          W3Th + (size_t)hp * HID, W3Tm + (size_t)hp * HID,
          h2, h3, hp > 0 ? 1 : 0, nG23);
    }
    // final gemm23 for head 7 (emb slot 1)
    gemm23_k<<<dim3(GM1, 1, 2), 256, 0, stream>>>(
        embH + HID, embM + HID, embL + HID, ldE,
        W2Th + (size_t)7 * HID, W2Tm + (size_t)7 * HID, W2Tl + (size_t)7 * HID,
        W3Th + (size_t)7 * HID, W3Tm + (size_t)7 * HID, HID * HEADS,
        h2, h3, OUTF, N, HID, 1);
  } else {
    // ---- fallback: sequential everything ----
    k_asad1<<<gW, 256, 0, stream>>>(x, watt, asall, adall, N);
    k_init_deg<<<gN, 256, 0, stream>>>(wp1, N);
    k_count<<<gE, 256, 0, stream>>>(ei1, flag, wp1, E);
    k_scan<<<1, 1024, 0, stream>>>(wp1, rp1, N);
    k_fill_self<<<gN, 256, 0, stream>>>(rp1, wp1, col1, N);
    k_fill_edges<<<gE, 256, 0, stream>>>(ei1, flag, wp1, col1, E);
    k_init_deg<<<gN, 256, 0, stream>>>(wp2, N);
    k_count<<<gE, 256, 0, stream>>>(ei2, flag, wp2, E);
    k_scan<<<1, 1024, 0, stream>>>(wp2, rp2, N);
    k_fill_self<<<gN, 256, 0, stream>>>(rp2, wp2, col2, N);
    k_fill_edges<<<gE, 256, 0, stream>>>(ei2, flag, wp2, col2, E);
    for (int h = 0; h < HEADS; ++h) {
      gemm1_k<<<dim3(GM1, 2), 256, 0, stream>>>(
          x, IN_F,
          W1Th + (size_t)h * HID * IN_F, W1Tm + (size_t)h * HID * IN_F,
          W1Tl + (size_t)h * HID * IN_F, IN_F, h1hA, HID, N, IN_F);
      aggr_l1_fused<<<gW, 256, 0, stream>>>(
          rp1, col1, asall + (size_t)h * N, adall + (size_t)h * N, h1hA,
          b1 + (size_t)h * HID, embH, embM, embL, 0, ldE, N);
      gemm23_k<<<dim3(GM1, 1, 2), 256, 0, stream>>>(
          embH, embM, embL, ldE,
          W2Th + (size_t)h * HID, W2Tm + (size_t)h * HID,
          W2Tl + (size_t)h * HID,
          W3Th + (size_t)h * HID, W3Tm + (size_t)h * HID, HID * HEADS,
          h2, h3, OUTF, N, HID, h > 0 ? 1 : 0);
    }
  }

  // ---- layer 2 attention + aggregation (heads=1), dual dispatches ----
  att_dot_dual<<<2 * gW, 256, 0, stream>>>(
      h2, h3, attS2, attD2, attS3, attD3, as2, ad2, as3, ad3, N, gW);
  aggr_l2_dual<<<2 * gW, 256, 0, stream>>>(
      rp1, col1, as2, ad2, h2, b2, x1, pred,
      rp2, col2, as3, ad3, h3, b3, x2, N, gW);
}